// Round 3
// baseline (199.305 us; speedup 1.0000x reference)
//
#include <hip/hip_runtime.h>
#include <math.h>

#define NMAX 4096
#define N4   (NMAX/4)
#define CH4  (N4/4)     // visc velocity staging chunk (in float4)

// n assumed multiple of 16 (reference: N=4096).

constexpr float RADIUS       = 0.1f;
constexpr float DT           = 1.0f / 60.0f;
constexpr float MAX_VEL      = 3.0f;               // 0.5*0.1/DT
constexpr float VISCOSITY    = 60.0f;
constexpr float DENSITY_REST = 17510.1f;
constexpr float STIFFNESS    = 2.99e-11f;
constexpr float EPS          = 1e-8f;
constexpr float SPIKY_C      = (float)(15.0 / (3.14159265358979323846 * 1e-6)); // 15/(pi*R^6)

__device__ __forceinline__ float elem(const float4& v, int c) {
    return reinterpret_cast<const float*>(&v)[c];
}

// Device-coherent (sc1) scalar store: write-through past the non-coherent
// local L2 so peer XCDs can see it after the barrier.
__device__ __forceinline__ void store_dc(float* p, float v) {
    __hip_atomic_store(p, v, __ATOMIC_RELAXED, __HIP_MEMORY_SCOPE_AGENT);
}

// All-to-all flag grid barrier (no atomics, no contended line).
// flags: nb slots, 16 uints (64 B) apart, zeroed by host. Monotonic phase.
// Block b arrives by storing `phase` to its own flag; threads t<nb poll flag t.
// __syncthreads before arrival drains each wave's vmcnt (sc1 data stores are
// at the coherence point when their vmcnt retires), so flag => data visible.
__device__ __forceinline__ void grid_barrier(unsigned int* flags, unsigned int phase, int nb) {
    __syncthreads();
    if (threadIdx.x == 0)
        __hip_atomic_store(&flags[(unsigned)blockIdx.x * 16], phase,
                           __ATOMIC_RELAXED, __HIP_MEMORY_SCOPE_AGENT);
    if (threadIdx.x < (unsigned)nb) {
        while (__hip_atomic_load(&flags[threadIdx.x * 16], __ATOMIC_RELAXED,
                                 __HIP_MEMORY_SCOPE_AGENT) < phase) {
            __builtin_amdgcn_s_sleep(1);
        }
    }
    __builtin_amdgcn_fence(__ATOMIC_ACQUIRE, "agent");   // invalidate stale L1/L2 lines
    __syncthreads();
}

// Compute predicted positions for the whole system into LDS (SoA float4).
__device__ __forceinline__ void predict_to_lds(const float4* __restrict__ locs4,
                                               const float4* __restrict__ vel4,
                                               float4* sx, float4* sy, float4* sz,
                                               int n4, int tid, int nthreads) {
    for (int g = tid; g < n4; g += nthreads) {
        float lo[12], ve[12];
        *(float4*)&lo[0] = locs4[3*g];   *(float4*)&lo[4] = locs4[3*g+1]; *(float4*)&lo[8] = locs4[3*g+2];
        *(float4*)&ve[0] = vel4[3*g];    *(float4*)&ve[4] = vel4[3*g+1];  *(float4*)&ve[8] = vel4[3*g+2];
        float X[4], Y[4], Z[4];
#pragma unroll
        for (int p = 0; p < 4; ++p) {
            float vx = ve[3*p], vy = ve[3*p+1] - 9.8f * DT, vz = ve[3*p+2];
            float vv = sqrtf(vx*vx + vy*vy + vz*vz);
            float s  = fminf(MAX_VEL / (vv + 1e-4f), 1.0f);
            X[p] = lo[3*p]   + DT * vx * s;
            Y[p] = lo[3*p+1] + DT * vy * s;
            Z[p] = lo[3*p+2] + DT * vz * s;
        }
        sx[g] = make_float4(X[0], X[1], X[2], X[3]);
        sy[g] = make_float4(Y[0], Y[1], Y[2], Y[3]);
        sz[g] = make_float4(Z[0], Z[1], Z[2], Z[3]);
    }
}

// rho body (2 particles/wave): writes pre-scaled L = -3C*lam for i0, i0+1.
__device__ __forceinline__ void rho_body2(const float4* sx, const float4* sy, const float4* sz,
                                          float* __restrict__ lam, int n4, int i0, int lane) {
    const float* fx = (const float*)sx; const float* fy = (const float*)sy; const float* fz = (const float*)sz;
    const float xi0 = fx[i0],   yi0 = fy[i0],   zi0 = fz[i0];
    const float xi1 = fx[i0+1], yi1 = fy[i0+1], zi1 = fz[i0+1];
    float S0 = 0.f, S1 = 0.f;
    for (int k = lane; k < n4; k += 64) {
        float4 X = sx[k], Y = sy[k], Z = sz[k];
#pragma unroll
        for (int c = 0; c < 4; ++c) {
            float xj = elem(X,c), yj = elem(Y,c), zj = elem(Z,c);
            {
                float dx = xi0-xj, dy = yi0-yj, dz = zi0-zj;
                float d2 = fmaf(dx,dx,EPS); d2 = fmaf(dy,dy,d2); d2 = fmaf(dz,dz,d2);
                float t  = fmaxf(RADIUS - __builtin_amdgcn_sqrtf(d2), 0.f);
                S0 = fmaf(t*t, t, S0);
            }
            {
                float dx = xi1-xj, dy = yi1-yj, dz = zi1-zj;
                float d2 = fmaf(dx,dx,EPS); d2 = fmaf(dy,dy,d2); d2 = fmaf(dz,dz,d2);
                float t  = fmaxf(RADIUS - __builtin_amdgcn_sqrtf(d2), 0.f);
                S1 = fmaf(t*t, t, S1);
            }
        }
    }
    for (int off = 32; off > 0; off >>= 1) {
        S0 += __shfl_down(S0, off);
        S1 += __shfl_down(S1, off);
    }
    if (lane == 0) {
        const float ts  = RADIUS - __builtin_amdgcn_sqrtf(EPS);  // exact self-term
        const float TS3 = ts*ts*ts;
        const float k3  = 3.f * SPIKY_C * STIFFNESS;             // L = -3C*lam
        store_dc(&lam[i0],   k3 * (SPIKY_C * (S0 - TS3) - DENSITY_REST));
        store_dc(&lam[i0+1], k3 * (SPIKY_C * (S1 - TS3) - DENSITY_REST));
    }
}

// delta body (2 particles/wave). Writes new pred (SoA, device-coherent) and
// optionally final outputs.
__device__ __forceinline__ void delta_body2(const float4* sx, const float4* sy, const float4* sz,
                                            const float4* sl,
                                            float* __restrict__ qx, float* __restrict__ qy, float* __restrict__ qz,
                                            const float* __restrict__ locs,
                                            float* __restrict__ out_pred,
                                            float* __restrict__ vnx, float* __restrict__ vny, float* __restrict__ vnz,
                                            int n4, int i0, int lane) {
    const float* fx = (const float*)sx; const float* fy = (const float*)sy;
    const float* fz = (const float*)sz; const float* fl = (const float*)sl;
    const float xi0 = fx[i0],   yi0 = fy[i0],   zi0 = fz[i0],   L0 = fl[i0];
    const float xi1 = fx[i0+1], yi1 = fy[i0+1], zi1 = fz[i0+1], L1 = fl[i0+1];
    float ax0=0.f, ay0=0.f, az0=0.f, ax1=0.f, ay1=0.f, az1=0.f;
    for (int k = lane; k < n4; k += 64) {
        float4 X = sx[k], Y = sy[k], Z = sz[k], L = sl[k];
#pragma unroll
        for (int c = 0; c < 4; ++c) {
            float xj = elem(X,c), yj = elem(Y,c), zj = elem(Z,c), Lj = elem(L,c);
            {
                float dx = xi0-xj, dy = yi0-yj, dz = zi0-zj;
                float d2 = fmaf(dx,dx,EPS); d2 = fmaf(dy,dy,d2); d2 = fmaf(dz,dz,d2);
                float rinv = __builtin_amdgcn_rsqf(d2);
                float t  = fmaxf(RADIUS - d2*rinv, 0.f);
                float cf = (L0 + Lj) * (t*t) * rinv;
                ax0 = fmaf(cf, dx, ax0); ay0 = fmaf(cf, dy, ay0); az0 = fmaf(cf, dz, az0);
            }
            {
                float dx = xi1-xj, dy = yi1-yj, dz = zi1-zj;
                float d2 = fmaf(dx,dx,EPS); d2 = fmaf(dy,dy,d2); d2 = fmaf(dz,dz,d2);
                float rinv = __builtin_amdgcn_rsqf(d2);
                float t  = fmaxf(RADIUS - d2*rinv, 0.f);
                float cf = (L1 + Lj) * (t*t) * rinv;
                ax1 = fmaf(cf, dx, ax1); ay1 = fmaf(cf, dy, ay1); az1 = fmaf(cf, dz, az1);
            }
        }
    }
    for (int off = 32; off > 0; off >>= 1) {
        ax0 += __shfl_down(ax0, off); ay0 += __shfl_down(ay0, off); az0 += __shfl_down(az0, off);
        ax1 += __shfl_down(ax1, off); ay1 += __shfl_down(ay1, off); az1 += __shfl_down(az1, off);
    }
    if (lane == 0) {
        float nx0 = xi0+ax0, ny0 = yi0+ay0, nz0 = zi0+az0;
        float nx1 = xi1+ax1, ny1 = yi1+ay1, nz1 = zi1+az1;
        store_dc(&qx[i0], nx0);   store_dc(&qy[i0], ny0);   store_dc(&qz[i0], nz0);
        store_dc(&qx[i0+1], nx1); store_dc(&qy[i0+1], ny1); store_dc(&qz[i0+1], nz1);
        if (out_pred) {
#pragma unroll
            for (int u = 0; u < 2; ++u) {
                int i = i0 + u;
                float nx_ = u ? nx1 : nx0, ny_ = u ? ny1 : ny0, nz_ = u ? nz1 : nz0;
                out_pred[3*i+0] = nx_; out_pred[3*i+1] = ny_; out_pred[3*i+2] = nz_;
                store_dc(&vnx[i], (nx_ - locs[3*i+0]) * (1.0f/DT));
                store_dc(&vny[i], (ny_ - locs[3*i+1]) * (1.0f/DT));
                store_dc(&vnz[i], (nz_ - locs[3*i+2]) * (1.0f/DT));
            }
        }
    }
}

// ---------------- single fused kernel (plain launch, guaranteed co-resident:
// 64 KB LDS / 512 thr / 60 VGPR -> 2 blocks/CU capacity, grid = 256 <= 512 slots)

__global__ __launch_bounds__(512, 2) void k_fused(const float4* __restrict__ locs4,
                                                  const float4* __restrict__ vel4,
                                                  const float* __restrict__ locs,
                                                  float* __restrict__ px, float* __restrict__ py,
                                                  float* __restrict__ pz,
                                                  float* __restrict__ lam,
                                                  float* __restrict__ vnx, float* __restrict__ vny,
                                                  float* __restrict__ vnz,
                                                  float* __restrict__ out,
                                                  unsigned int* __restrict__ flags, int n) {
    __shared__ float4 sx[N4], sy[N4], sz[N4], sl[N4];   // 64 KB
    const int n4   = n >> 2;
    const int lane = threadIdx.x & 63;
    const int i0   = blockIdx.x * 16 + (threadIdx.x >> 6) * 2;
    const int nb   = gridDim.x;
    unsigned int phase = 0;

    // predict: every block builds the full predicted-position copy in LDS
    // (no global exchange needed for iteration 1's rho).
    predict_to_lds(locs4, vel4, sx, sy, sz, n4, threadIdx.x, 512);
    __syncthreads();

    for (int it = 0; it < 3; ++it) {
        const bool last = (it == 2);

        // rho: LDS pred -> L[i0..i0+1] (global, device-coherent)
        rho_body2(sx, sy, sz, lam, n4, i0, lane);
        grid_barrier(flags, ++phase, nb);

        // stage L into LDS
        for (int idx = threadIdx.x; idx < n4; idx += 512) sl[idx] = ((const float4*)lam)[idx];
        __syncthreads();

        // delta: LDS pred + LDS L -> new pred for own particles (global SoA);
        // on last iteration also emit out_pred and new_vel.
        delta_body2(sx, sy, sz, sl, px, py, pz,
                    last ? locs : nullptr, last ? out : nullptr, vnx, vny, vnz,
                    n4, i0, lane);
        grid_barrier(flags, ++phase, nb);

        // re-stage updated pred into LDS (used by next rho, or by visc)
        for (int idx = threadIdx.x; idx < n4; idx += 512) {
            sx[idx] = ((const float4*)px)[idx];
            sy[idx] = ((const float4*)py)[idx];
            sz[idx] = ((const float4*)pz)[idx];
        }
        __syncthreads();
    }

    // ---- XSPH viscosity on final positions (pred already in sx/sy/sz) ----
    const float* fpx = (const float*)sx; const float* fpy = (const float*)sy; const float* fpz = (const float*)sz;
    const float xi0 = fpx[i0],   yi0 = fpy[i0],   zi0 = fpz[i0];
    const float xi1 = fpx[i0+1], yi1 = fpy[i0+1], zi1 = fpz[i0+1];
    const float vix0 = vnx[i0],   viy0 = vny[i0],   viz0 = vnz[i0];
    const float vix1 = vnx[i0+1], viy1 = vny[i0+1], viz1 = vnz[i0+1];
    float ws0=0.f, ax0=0.f, ay0=0.f, az0=0.f;
    float ws1=0.f, ax1=0.f, ay1=0.f, az1=0.f;
    const float4* vx4 = (const float4*)vnx;
    const float4* vy4 = (const float4*)vny;
    const float4* vz4 = (const float4*)vnz;
    for (int ch = 0; ch < 4; ++ch) {
        __syncthreads();
        for (int idx = threadIdx.x; idx < CH4; idx += 512) {
            sl[idx]         = vx4[ch*CH4+idx];
            sl[CH4+idx]     = vy4[ch*CH4+idx];
            sl[2*CH4+idx]   = vz4[ch*CH4+idx];
        }
        __syncthreads();
        for (int k = lane; k < CH4; k += 64) {
            float4 X = sx[ch*CH4+k], Y = sy[ch*CH4+k], Z = sz[ch*CH4+k];
            float4 VX = sl[k], VY = sl[CH4+k], VZ = sl[2*CH4+k];
#pragma unroll
            for (int c = 0; c < 4; ++c) {
                float xj = elem(X,c), yj = elem(Y,c), zj = elem(Z,c);
                float vxj = elem(VX,c), vyj = elem(VY,c), vzj = elem(VZ,c);
                {
                    float dx = xi0-xj, dy = yi0-yj, dz = zi0-zj;
                    float d2 = fmaf(dx,dx,EPS); d2 = fmaf(dy,dy,d2); d2 = fmaf(dz,dz,d2);
                    float t  = fmaxf(RADIUS - __builtin_amdgcn_sqrtf(d2), 0.f);
                    float w  = t*t*t;
                    ws0 += w;
                    ax0 = fmaf(w, vxj, ax0); ay0 = fmaf(w, vyj, ay0); az0 = fmaf(w, vzj, az0);
                }
                {
                    float dx = xi1-xj, dy = yi1-yj, dz = zi1-zj;
                    float d2 = fmaf(dx,dx,EPS); d2 = fmaf(dy,dy,d2); d2 = fmaf(dz,dz,d2);
                    float t  = fmaxf(RADIUS - __builtin_amdgcn_sqrtf(d2), 0.f);
                    float w  = t*t*t;
                    ws1 += w;
                    ax1 = fmaf(w, vxj, ax1); ay1 = fmaf(w, vyj, ay1); az1 = fmaf(w, vzj, az1);
                }
            }
        }
    }
    for (int off = 32; off > 0; off >>= 1) {
        ws0 += __shfl_down(ws0, off); ax0 += __shfl_down(ax0, off);
        ay0 += __shfl_down(ay0, off); az0 += __shfl_down(az0, off);
        ws1 += __shfl_down(ws1, off); ax1 += __shfl_down(ax1, off);
        ay1 += __shfl_down(ay1, off); az1 += __shfl_down(az1, off);
    }
    if (lane == 0) {
        constexpr float K = VISCOSITY * DT / DENSITY_REST;
        const float KC = K * SPIKY_C;   // C folded here
#pragma unroll
        for (int u = 0; u < 2; ++u) {
            int i = i0 + u;
            float vix = (u ? vix1 : vix0), viy = (u ? viy1 : viy0), viz = (u ? viz1 : viz0);
            float sw  = (u ? ws1 : ws0);
            float sax = (u ? ax1 : ax0), say = (u ? ay1 : ay0), saz = (u ? az1 : az0);
            float nvx = vix + KC * (sax - sw * vix);
            float nvy = viy + KC * (say - sw * viy);
            float nvz = viz + KC * (saz - sw * viz);
            float vv = sqrtf(nvx*nvx + nvy*nvy + nvz*nvz);
            float s  = fminf(MAX_VEL / (vv + 1e-4f), 1.0f);
            out[3*n + 3*i + 0] = nvx * s;
            out[3*n + 3*i + 1] = nvy * s;
            out[3*n + 3*i + 2] = nvz * s;
        }
    }
}

extern "C" void kernel_launch(void* const* d_in, const int* in_sizes, int n_in,
                              void* d_out, int out_size, void* d_ws, size_t ws_size,
                              hipStream_t stream) {
    const float* locs = (const float*)d_in[0];
    const float* vel  = (const float*)d_in[1];
    const float4* locs4 = (const float4*)locs;
    const float4* vel4  = (const float4*)vel;
    float* out = (float*)d_out;
    int n = in_sizes[0] / 3;

    float* w = (float*)d_ws;
    float* px  = w;        float* py  = px + n;   float* pz  = py + n;
    float* lam = pz + n;
    float* vnx = lam + n;  float* vny = vnx + n;  float* vnz = vny + n;
    unsigned int* flags = (unsigned int*)(w + 10 * n);   // 64B-strided flags, after arrays

    int nb = n / 16;   // 8 waves/block, 2 particles/wave -> 256 blocks for n=4096

    // zero the flag region (stream-ordered, graph-capturable)
    hipMemsetAsync((void*)flags, 0, (size_t)nb * 64, stream);

    k_fused<<<dim3(nb), dim3(512), 0, stream>>>(locs4, vel4, locs,
                                                px, py, pz, lam,
                                                vnx, vny, vnz,
                                                out, flags, n);
}

// Round 4
// 145.528 us; speedup vs baseline: 1.3695x; 1.3695x over previous
//
#include <hip/hip_runtime.h>
#include <math.h>

#define NMAX 4096
#define N4   (NMAX/4)
#define CH4  (N4/4)     // visc velocity staging chunk (in float4)

// n assumed multiple of 256 (reference: N=4096) so nb = n/16 is a multiple of 16.

constexpr float RADIUS       = 0.1f;
constexpr float DT           = 1.0f / 60.0f;
constexpr float MAX_VEL      = 3.0f;               // 0.5*0.1/DT
constexpr float VISCOSITY    = 60.0f;
constexpr float DENSITY_REST = 17510.1f;
constexpr float STIFFNESS    = 2.99e-11f;
constexpr float EPS          = 1e-8f;
constexpr float SPIKY_C      = (float)(15.0 / (3.14159265358979323846 * 1e-6)); // 15/(pi*R^6)

#define BAR_STRIDE 16   // uints (64 B) between barrier words

__device__ __forceinline__ float elem(const float4& v, int c) {
    return reinterpret_cast<const float*>(&v)[c];
}

// Device-coherent scalar store: write-through past the non-coherent local L2
// so peer XCDs can see it after the barrier.
__device__ __forceinline__ void store_dc(float* p, float v) {
    __hip_atomic_store(p, v, __ATOMIC_RELAXED, __HIP_MEMORY_SCOPE_AGENT);
}

// Two-level tree grid barrier, monotonic phases (no reset needed).
// ws layout (64B-strided uints, zeroed by host):
//   ws[g*16]   g=0..ngroups-1 : group arrival counters (16 blocks/group)
//   ws[ngroups*16]            : root counter (one arrival per group per phase)
//   ws[(ngroups+1)*16]        : release word (stores current phase)
// Arrival: 16 serialized memory-side RMWs per group line (parallel across
// group lines) + ngroups RMWs on root + 1 release store.
// Release: every block's thread 0 polls the single release line (same-line
// reads are cheap at the coherence point), then acquire-fence (buffer_inv
// covers this CU's L1) + __syncthreads releases the block.
// __syncthreads before arrival drains each wave's vmcnt, so all prior sc1
// data stores are at the coherence point before the flag RMW.
__device__ __forceinline__ void grid_barrier(unsigned int* ws, unsigned int phase,
                                             unsigned int ngroups) {
    __syncthreads();
    if (threadIdx.x == 0) {
        const unsigned g = (unsigned)blockIdx.x >> 4;   // 16 blocks per group
        unsigned a = __hip_atomic_fetch_add(&ws[g * BAR_STRIDE], 1u,
                                            __ATOMIC_RELAXED, __HIP_MEMORY_SCOPE_AGENT);
        if (a == phase * 16u - 1u) {                    // last arriver of this group
            unsigned r = __hip_atomic_fetch_add(&ws[ngroups * BAR_STRIDE], 1u,
                                                __ATOMIC_RELAXED, __HIP_MEMORY_SCOPE_AGENT);
            if (r == phase * ngroups - 1u)              // last group overall
                __hip_atomic_store(&ws[(ngroups + 1u) * BAR_STRIDE], phase,
                                   __ATOMIC_RELAXED, __HIP_MEMORY_SCOPE_AGENT);
        }
        while (__hip_atomic_load(&ws[(ngroups + 1u) * BAR_STRIDE], __ATOMIC_RELAXED,
                                 __HIP_MEMORY_SCOPE_AGENT) < phase) {
            __builtin_amdgcn_s_sleep(1);
        }
        __builtin_amdgcn_fence(__ATOMIC_ACQUIRE, "agent");   // invalidate stale L1/L2 lines
    }
    __syncthreads();
}

// Compute predicted positions for the whole system into LDS (SoA float4).
__device__ __forceinline__ void predict_to_lds(const float4* __restrict__ locs4,
                                               const float4* __restrict__ vel4,
                                               float4* sx, float4* sy, float4* sz,
                                               int n4, int tid, int nthreads) {
    for (int g = tid; g < n4; g += nthreads) {
        float lo[12], ve[12];
        *(float4*)&lo[0] = locs4[3*g];   *(float4*)&lo[4] = locs4[3*g+1]; *(float4*)&lo[8] = locs4[3*g+2];
        *(float4*)&ve[0] = vel4[3*g];    *(float4*)&ve[4] = vel4[3*g+1];  *(float4*)&ve[8] = vel4[3*g+2];
        float X[4], Y[4], Z[4];
#pragma unroll
        for (int p = 0; p < 4; ++p) {
            float vx = ve[3*p], vy = ve[3*p+1] - 9.8f * DT, vz = ve[3*p+2];
            float vv = sqrtf(vx*vx + vy*vy + vz*vz);
            float s  = fminf(MAX_VEL / (vv + 1e-4f), 1.0f);
            X[p] = lo[3*p]   + DT * vx * s;
            Y[p] = lo[3*p+1] + DT * vy * s;
            Z[p] = lo[3*p+2] + DT * vz * s;
        }
        sx[g] = make_float4(X[0], X[1], X[2], X[3]);
        sy[g] = make_float4(Y[0], Y[1], Y[2], Y[3]);
        sz[g] = make_float4(Z[0], Z[1], Z[2], Z[3]);
    }
}

// rho body (2 particles/wave): writes pre-scaled L = -3C*lam for i0, i0+1.
__device__ __forceinline__ void rho_body2(const float4* sx, const float4* sy, const float4* sz,
                                          float* __restrict__ lam, int n4, int i0, int lane) {
    const float* fx = (const float*)sx; const float* fy = (const float*)sy; const float* fz = (const float*)sz;
    const float xi0 = fx[i0],   yi0 = fy[i0],   zi0 = fz[i0];
    const float xi1 = fx[i0+1], yi1 = fy[i0+1], zi1 = fz[i0+1];
    float S0 = 0.f, S1 = 0.f;
    for (int k = lane; k < n4; k += 64) {
        float4 X = sx[k], Y = sy[k], Z = sz[k];
#pragma unroll
        for (int c = 0; c < 4; ++c) {
            float xj = elem(X,c), yj = elem(Y,c), zj = elem(Z,c);
            {
                float dx = xi0-xj, dy = yi0-yj, dz = zi0-zj;
                float d2 = fmaf(dx,dx,EPS); d2 = fmaf(dy,dy,d2); d2 = fmaf(dz,dz,d2);
                float t  = fmaxf(RADIUS - __builtin_amdgcn_sqrtf(d2), 0.f);
                S0 = fmaf(t*t, t, S0);
            }
            {
                float dx = xi1-xj, dy = yi1-yj, dz = zi1-zj;
                float d2 = fmaf(dx,dx,EPS); d2 = fmaf(dy,dy,d2); d2 = fmaf(dz,dz,d2);
                float t  = fmaxf(RADIUS - __builtin_amdgcn_sqrtf(d2), 0.f);
                S1 = fmaf(t*t, t, S1);
            }
        }
    }
    for (int off = 32; off > 0; off >>= 1) {
        S0 += __shfl_down(S0, off);
        S1 += __shfl_down(S1, off);
    }
    if (lane == 0) {
        const float ts  = RADIUS - __builtin_amdgcn_sqrtf(EPS);  // exact self-term
        const float TS3 = ts*ts*ts;
        const float k3  = 3.f * SPIKY_C * STIFFNESS;             // L = -3C*lam
        store_dc(&lam[i0],   k3 * (SPIKY_C * (S0 - TS3) - DENSITY_REST));
        store_dc(&lam[i0+1], k3 * (SPIKY_C * (S1 - TS3) - DENSITY_REST));
    }
}

// delta body (2 particles/wave). Writes new pred (SoA, device-coherent) and
// optionally final outputs.
__device__ __forceinline__ void delta_body2(const float4* sx, const float4* sy, const float4* sz,
                                            const float4* sl,
                                            float* __restrict__ qx, float* __restrict__ qy, float* __restrict__ qz,
                                            const float* __restrict__ locs,
                                            float* __restrict__ out_pred,
                                            float* __restrict__ vnx, float* __restrict__ vny, float* __restrict__ vnz,
                                            int n4, int i0, int lane) {
    const float* fx = (const float*)sx; const float* fy = (const float*)sy;
    const float* fz = (const float*)sz; const float* fl = (const float*)sl;
    const float xi0 = fx[i0],   yi0 = fy[i0],   zi0 = fz[i0],   L0 = fl[i0];
    const float xi1 = fx[i0+1], yi1 = fy[i0+1], zi1 = fz[i0+1], L1 = fl[i0+1];
    float ax0=0.f, ay0=0.f, az0=0.f, ax1=0.f, ay1=0.f, az1=0.f;
    for (int k = lane; k < n4; k += 64) {
        float4 X = sx[k], Y = sy[k], Z = sz[k], L = sl[k];
#pragma unroll
        for (int c = 0; c < 4; ++c) {
            float xj = elem(X,c), yj = elem(Y,c), zj = elem(Z,c), Lj = elem(L,c);
            {
                float dx = xi0-xj, dy = yi0-yj, dz = zi0-zj;
                float d2 = fmaf(dx,dx,EPS); d2 = fmaf(dy,dy,d2); d2 = fmaf(dz,dz,d2);
                float rinv = __builtin_amdgcn_rsqf(d2);
                float t  = fmaxf(RADIUS - d2*rinv, 0.f);
                float cf = (L0 + Lj) * (t*t) * rinv;
                ax0 = fmaf(cf, dx, ax0); ay0 = fmaf(cf, dy, ay0); az0 = fmaf(cf, dz, az0);
            }
            {
                float dx = xi1-xj, dy = yi1-yj, dz = zi1-zj;
                float d2 = fmaf(dx,dx,EPS); d2 = fmaf(dy,dy,d2); d2 = fmaf(dz,dz,d2);
                float rinv = __builtin_amdgcn_rsqf(d2);
                float t  = fmaxf(RADIUS - d2*rinv, 0.f);
                float cf = (L1 + Lj) * (t*t) * rinv;
                ax1 = fmaf(cf, dx, ax1); ay1 = fmaf(cf, dy, ay1); az1 = fmaf(cf, dz, az1);
            }
        }
    }
    for (int off = 32; off > 0; off >>= 1) {
        ax0 += __shfl_down(ax0, off); ay0 += __shfl_down(ay0, off); az0 += __shfl_down(az0, off);
        ax1 += __shfl_down(ax1, off); ay1 += __shfl_down(ay1, off); az1 += __shfl_down(az1, off);
    }
    if (lane == 0) {
        float nx0 = xi0+ax0, ny0 = yi0+ay0, nz0 = zi0+az0;
        float nx1 = xi1+ax1, ny1 = yi1+ay1, nz1 = zi1+az1;
        store_dc(&qx[i0], nx0);   store_dc(&qy[i0], ny0);   store_dc(&qz[i0], nz0);
        store_dc(&qx[i0+1], nx1); store_dc(&qy[i0+1], ny1); store_dc(&qz[i0+1], nz1);
        if (out_pred) {
#pragma unroll
            for (int u = 0; u < 2; ++u) {
                int i = i0 + u;
                float nx_ = u ? nx1 : nx0, ny_ = u ? ny1 : ny0, nz_ = u ? nz1 : nz0;
                out_pred[3*i+0] = nx_; out_pred[3*i+1] = ny_; out_pred[3*i+2] = nz_;
                store_dc(&vnx[i], (nx_ - locs[3*i+0]) * (1.0f/DT));
                store_dc(&vny[i], (ny_ - locs[3*i+1]) * (1.0f/DT));
                store_dc(&vnz[i], (nz_ - locs[3*i+2]) * (1.0f/DT));
            }
        }
    }
}

// ---------------- single fused kernel (plain launch, guaranteed co-resident:
// 64 KB LDS / 512 thr / 60 VGPR -> 2 blocks/CU capacity, grid = 256 <= 512 slots)

__global__ __launch_bounds__(512, 2) void k_fused(const float4* __restrict__ locs4,
                                                  const float4* __restrict__ vel4,
                                                  const float* __restrict__ locs,
                                                  float* __restrict__ px, float* __restrict__ py,
                                                  float* __restrict__ pz,
                                                  float* __restrict__ lam,
                                                  float* __restrict__ vnx, float* __restrict__ vny,
                                                  float* __restrict__ vnz,
                                                  float* __restrict__ out,
                                                  unsigned int* __restrict__ bar_ws, int n) {
    __shared__ float4 sx[N4], sy[N4], sz[N4], sl[N4];   // 64 KB
    const int n4   = n >> 2;
    const int lane = threadIdx.x & 63;
    const int i0   = blockIdx.x * 16 + (threadIdx.x >> 6) * 2;
    const unsigned int ngroups = (unsigned)gridDim.x >> 4;   // 16 blocks per group
    unsigned int phase = 0;

    // predict: every block builds the full predicted-position copy in LDS
    // (no global exchange needed for iteration 1's rho).
    predict_to_lds(locs4, vel4, sx, sy, sz, n4, threadIdx.x, 512);
    __syncthreads();

    for (int it = 0; it < 3; ++it) {
        const bool last = (it == 2);

        // rho: LDS pred -> L[i0..i0+1] (global, device-coherent)
        rho_body2(sx, sy, sz, lam, n4, i0, lane);
        grid_barrier(bar_ws, ++phase, ngroups);

        // stage L into LDS
        for (int idx = threadIdx.x; idx < n4; idx += 512) sl[idx] = ((const float4*)lam)[idx];
        __syncthreads();

        // delta: LDS pred + LDS L -> new pred for own particles (global SoA);
        // on last iteration also emit out_pred and new_vel.
        delta_body2(sx, sy, sz, sl, px, py, pz,
                    last ? locs : nullptr, last ? out : nullptr, vnx, vny, vnz,
                    n4, i0, lane);
        grid_barrier(bar_ws, ++phase, ngroups);

        // re-stage updated pred into LDS (used by next rho, or by visc)
        for (int idx = threadIdx.x; idx < n4; idx += 512) {
            sx[idx] = ((const float4*)px)[idx];
            sy[idx] = ((const float4*)py)[idx];
            sz[idx] = ((const float4*)pz)[idx];
        }
        __syncthreads();
    }

    // ---- XSPH viscosity on final positions (pred already in sx/sy/sz) ----
    const float* fpx = (const float*)sx; const float* fpy = (const float*)sy; const float* fpz = (const float*)sz;
    const float xi0 = fpx[i0],   yi0 = fpy[i0],   zi0 = fpz[i0];
    const float xi1 = fpx[i0+1], yi1 = fpy[i0+1], zi1 = fpz[i0+1];
    const float vix0 = vnx[i0],   viy0 = vny[i0],   viz0 = vnz[i0];
    const float vix1 = vnx[i0+1], viy1 = vny[i0+1], viz1 = vnz[i0+1];
    float ws0=0.f, ax0=0.f, ay0=0.f, az0=0.f;
    float ws1=0.f, ax1=0.f, ay1=0.f, az1=0.f;
    const float4* vx4 = (const float4*)vnx;
    const float4* vy4 = (const float4*)vny;
    const float4* vz4 = (const float4*)vnz;
    for (int ch = 0; ch < 4; ++ch) {
        __syncthreads();
        for (int idx = threadIdx.x; idx < CH4; idx += 512) {
            sl[idx]         = vx4[ch*CH4+idx];
            sl[CH4+idx]     = vy4[ch*CH4+idx];
            sl[2*CH4+idx]   = vz4[ch*CH4+idx];
        }
        __syncthreads();
        for (int k = lane; k < CH4; k += 64) {
            float4 X = sx[ch*CH4+k], Y = sy[ch*CH4+k], Z = sz[ch*CH4+k];
            float4 VX = sl[k], VY = sl[CH4+k], VZ = sl[2*CH4+k];
#pragma unroll
            for (int c = 0; c < 4; ++c) {
                float xj = elem(X,c), yj = elem(Y,c), zj = elem(Z,c);
                float vxj = elem(VX,c), vyj = elem(VY,c), vzj = elem(VZ,c);
                {
                    float dx = xi0-xj, dy = yi0-yj, dz = zi0-zj;
                    float d2 = fmaf(dx,dx,EPS); d2 = fmaf(dy,dy,d2); d2 = fmaf(dz,dz,d2);
                    float t  = fmaxf(RADIUS - __builtin_amdgcn_sqrtf(d2), 0.f);
                    float w  = t*t*t;
                    ws0 += w;
                    ax0 = fmaf(w, vxj, ax0); ay0 = fmaf(w, vyj, ay0); az0 = fmaf(w, vzj, az0);
                }
                {
                    float dx = xi1-xj, dy = yi1-yj, dz = zi1-zj;
                    float d2 = fmaf(dx,dx,EPS); d2 = fmaf(dy,dy,d2); d2 = fmaf(dz,dz,d2);
                    float t  = fmaxf(RADIUS - __builtin_amdgcn_sqrtf(d2), 0.f);
                    float w  = t*t*t;
                    ws1 += w;
                    ax1 = fmaf(w, vxj, ax1); ay1 = fmaf(w, vyj, ay1); az1 = fmaf(w, vzj, az1);
                }
            }
        }
    }
    for (int off = 32; off > 0; off >>= 1) {
        ws0 += __shfl_down(ws0, off); ax0 += __shfl_down(ax0, off);
        ay0 += __shfl_down(ay0, off); az0 += __shfl_down(az0, off);
        ws1 += __shfl_down(ws1, off); ax1 += __shfl_down(ax1, off);
        ay1 += __shfl_down(ay1, off); az1 += __shfl_down(az1, off);
    }
    if (lane == 0) {
        constexpr float K = VISCOSITY * DT / DENSITY_REST;
        const float KC = K * SPIKY_C;   // C folded here
#pragma unroll
        for (int u = 0; u < 2; ++u) {
            int i = i0 + u;
            float vix = (u ? vix1 : vix0), viy = (u ? viy1 : viy0), viz = (u ? viz1 : viz0);
            float sw  = (u ? ws1 : ws0);
            float sax = (u ? ax1 : ax0), say = (u ? ay1 : ay0), saz = (u ? az1 : az0);
            float nvx = vix + KC * (sax - sw * vix);
            float nvy = viy + KC * (say - sw * viy);
            float nvz = viz + KC * (saz - sw * viz);
            float vv = sqrtf(nvx*nvx + nvy*nvy + nvz*nvz);
            float s  = fminf(MAX_VEL / (vv + 1e-4f), 1.0f);
            out[3*n + 3*i + 0] = nvx * s;
            out[3*n + 3*i + 1] = nvy * s;
            out[3*n + 3*i + 2] = nvz * s;
        }
    }
}

extern "C" void kernel_launch(void* const* d_in, const int* in_sizes, int n_in,
                              void* d_out, int out_size, void* d_ws, size_t ws_size,
                              hipStream_t stream) {
    const float* locs = (const float*)d_in[0];
    const float* vel  = (const float*)d_in[1];
    const float4* locs4 = (const float4*)locs;
    const float4* vel4  = (const float4*)vel;
    float* out = (float*)d_out;
    int n = in_sizes[0] / 3;

    float* w = (float*)d_ws;
    float* px  = w;        float* py  = px + n;   float* pz  = py + n;
    float* lam = pz + n;
    float* vnx = lam + n;  float* vny = vnx + n;  float* vnz = vny + n;
    unsigned int* bar_ws = (unsigned int*)(w + 10 * n);   // barrier words after arrays

    int nb = n / 16;   // 8 waves/block, 2 particles/wave -> 256 blocks for n=4096

    // zero the barrier region: ngroups + root + release words, 64B-strided
    int ngroups = nb / 16;
    hipMemsetAsync((void*)bar_ws, 0, (size_t)(ngroups + 2) * 64, stream);

    k_fused<<<dim3(nb), dim3(512), 0, stream>>>(locs4, vel4, locs,
                                                px, py, pz, lam,
                                                vnx, vny, vnz,
                                                out, bar_ws, n);
}

// Round 5
// 141.595 us; speedup vs baseline: 1.4076x; 1.0278x over previous
//
#include <hip/hip_runtime.h>
#include <math.h>

#define NMAX 4096
#define N4   (NMAX/4)
#define CH4  (N4/4)       // visc velocity staging chunk (in float4)
#define NTHREADS 1024     // 16 waves/block, 1 particle/wave

// n assumed multiple of 512 (reference: N=4096).

constexpr float RADIUS       = 0.1f;
constexpr float DT           = 1.0f / 60.0f;
constexpr float MAX_VEL      = 3.0f;               // 0.5*0.1/DT
constexpr float VISCOSITY    = 60.0f;
constexpr float DENSITY_REST = 17510.1f;
constexpr float STIFFNESS    = 2.99e-11f;
constexpr float EPS          = 1e-8f;
constexpr float SPIKY_C      = (float)(15.0 / (3.14159265358979323846 * 1e-6)); // 15/(pi*R^6)

#define BAR_STRIDE 16   // uints (64 B) between barrier words

__device__ __forceinline__ float elem(const float4& v, int c) {
    return reinterpret_cast<const float*>(&v)[c];
}

// Device-coherent scalar store: write-through past the non-coherent local L2
// so peer XCDs can see it after the barrier.
__device__ __forceinline__ void store_dc(float* p, float v) {
    __hip_atomic_store(p, v, __ATOMIC_RELAXED, __HIP_MEMORY_SCOPE_AGENT);
}

// Two-level tree grid barrier, monotonic phases (no reset needed).
// ws layout (64B-strided uints, zeroed by host):
//   ws[g*16]   g=0..ngroups-1 : group arrival counters (16 blocks/group)
//   ws[ngroups*16]            : root counter
//   ws[(ngroups+1)*16]        : release word (stores current phase)
__device__ __forceinline__ void grid_barrier(unsigned int* ws, unsigned int phase,
                                             unsigned int ngroups) {
    __syncthreads();
    if (threadIdx.x == 0) {
        const unsigned g = (unsigned)blockIdx.x >> 4;   // 16 blocks per group
        unsigned a = __hip_atomic_fetch_add(&ws[g * BAR_STRIDE], 1u,
                                            __ATOMIC_RELAXED, __HIP_MEMORY_SCOPE_AGENT);
        if (a == phase * 16u - 1u) {                    // last arriver of this group
            unsigned r = __hip_atomic_fetch_add(&ws[ngroups * BAR_STRIDE], 1u,
                                                __ATOMIC_RELAXED, __HIP_MEMORY_SCOPE_AGENT);
            if (r == phase * ngroups - 1u)              // last group overall
                __hip_atomic_store(&ws[(ngroups + 1u) * BAR_STRIDE], phase,
                                   __ATOMIC_RELAXED, __HIP_MEMORY_SCOPE_AGENT);
        }
        while (__hip_atomic_load(&ws[(ngroups + 1u) * BAR_STRIDE], __ATOMIC_RELAXED,
                                 __HIP_MEMORY_SCOPE_AGENT) < phase) {
            __builtin_amdgcn_s_sleep(1);
        }
        __builtin_amdgcn_fence(__ATOMIC_ACQUIRE, "agent");   // invalidate stale L1/L2 lines
    }
    __syncthreads();
}

// Compute predicted positions for the whole system into LDS (SoA float4).
__device__ __forceinline__ void predict_to_lds(const float4* __restrict__ locs4,
                                               const float4* __restrict__ vel4,
                                               float4* sx, float4* sy, float4* sz,
                                               int n4, int tid, int nthreads) {
    for (int g = tid; g < n4; g += nthreads) {
        float lo[12], ve[12];
        *(float4*)&lo[0] = locs4[3*g];   *(float4*)&lo[4] = locs4[3*g+1]; *(float4*)&lo[8] = locs4[3*g+2];
        *(float4*)&ve[0] = vel4[3*g];    *(float4*)&ve[4] = vel4[3*g+1];  *(float4*)&ve[8] = vel4[3*g+2];
        float X[4], Y[4], Z[4];
#pragma unroll
        for (int p = 0; p < 4; ++p) {
            float vx = ve[3*p], vy = ve[3*p+1] - 9.8f * DT, vz = ve[3*p+2];
            float vv = sqrtf(vx*vx + vy*vy + vz*vz);
            float s  = fminf(MAX_VEL / (vv + 1e-4f), 1.0f);
            X[p] = lo[3*p]   + DT * vx * s;
            Y[p] = lo[3*p+1] + DT * vy * s;
            Z[p] = lo[3*p+2] + DT * vz * s;
        }
        sx[g] = make_float4(X[0], X[1], X[2], X[3]);
        sy[g] = make_float4(Y[0], Y[1], Y[2], Y[3]);
        sz[g] = make_float4(Z[0], Z[1], Z[2], Z[3]);
    }
}

// rho body (1 particle/wave, 2x k-unroll for ILP): writes L = -3C*lam for i.
__device__ __forceinline__ void rho_body1(const float4* sx, const float4* sy, const float4* sz,
                                          float* __restrict__ lam, int n4, int i, int lane) {
    const float* fx = (const float*)sx; const float* fy = (const float*)sy; const float* fz = (const float*)sz;
    const float xi = fx[i], yi = fy[i], zi = fz[i];
    float S0 = 0.f, S1 = 0.f;
    for (int k = lane; k < n4; k += 128) {
        float4 XA = sx[k],    YA = sy[k],    ZA = sz[k];
        float4 XB = sx[k+64], YB = sy[k+64], ZB = sz[k+64];
#pragma unroll
        for (int c = 0; c < 4; ++c) {
            {
                float dx = xi-elem(XA,c), dy = yi-elem(YA,c), dz = zi-elem(ZA,c);
                float d2 = fmaf(dx,dx,EPS); d2 = fmaf(dy,dy,d2); d2 = fmaf(dz,dz,d2);
                float t  = fmaxf(RADIUS - __builtin_amdgcn_sqrtf(d2), 0.f);
                S0 = fmaf(t*t, t, S0);
            }
            {
                float dx = xi-elem(XB,c), dy = yi-elem(YB,c), dz = zi-elem(ZB,c);
                float d2 = fmaf(dx,dx,EPS); d2 = fmaf(dy,dy,d2); d2 = fmaf(dz,dz,d2);
                float t  = fmaxf(RADIUS - __builtin_amdgcn_sqrtf(d2), 0.f);
                S1 = fmaf(t*t, t, S1);
            }
        }
    }
    float S = S0 + S1;
    for (int off = 32; off > 0; off >>= 1) S += __shfl_down(S, off);
    if (lane == 0) {
        const float ts  = RADIUS - __builtin_amdgcn_sqrtf(EPS);  // exact self-term
        const float TS3 = ts*ts*ts;
        const float k3  = 3.f * SPIKY_C * STIFFNESS;             // L = -3C*lam
        store_dc(&lam[i], k3 * (SPIKY_C * (S - TS3) - DENSITY_REST));
    }
}

// delta body (1 particle/wave, 2x k-unroll). Writes new pred (SoA, device-
// coherent) and optionally final outputs.
__device__ __forceinline__ void delta_body1(const float4* sx, const float4* sy, const float4* sz,
                                            const float4* sl,
                                            float* __restrict__ qx, float* __restrict__ qy, float* __restrict__ qz,
                                            const float* __restrict__ locs,
                                            float* __restrict__ out_pred,
                                            float* __restrict__ vnx, float* __restrict__ vny, float* __restrict__ vnz,
                                            int n4, int i, int lane) {
    const float* fx = (const float*)sx; const float* fy = (const float*)sy;
    const float* fz = (const float*)sz; const float* fl = (const float*)sl;
    const float xi = fx[i], yi = fy[i], zi = fz[i], Li = fl[i];
    float ax0=0.f, ay0=0.f, az0=0.f, ax1=0.f, ay1=0.f, az1=0.f;
    for (int k = lane; k < n4; k += 128) {
        float4 XA = sx[k],    YA = sy[k],    ZA = sz[k],    LA = sl[k];
        float4 XB = sx[k+64], YB = sy[k+64], ZB = sz[k+64], LB = sl[k+64];
#pragma unroll
        for (int c = 0; c < 4; ++c) {
            {
                float dx = xi-elem(XA,c), dy = yi-elem(YA,c), dz = zi-elem(ZA,c);
                float d2 = fmaf(dx,dx,EPS); d2 = fmaf(dy,dy,d2); d2 = fmaf(dz,dz,d2);
                float rinv = __builtin_amdgcn_rsqf(d2);
                float t  = fmaxf(RADIUS - d2*rinv, 0.f);
                float cf = (Li + elem(LA,c)) * (t*t) * rinv;
                ax0 = fmaf(cf, dx, ax0); ay0 = fmaf(cf, dy, ay0); az0 = fmaf(cf, dz, az0);
            }
            {
                float dx = xi-elem(XB,c), dy = yi-elem(YB,c), dz = zi-elem(ZB,c);
                float d2 = fmaf(dx,dx,EPS); d2 = fmaf(dy,dy,d2); d2 = fmaf(dz,dz,d2);
                float rinv = __builtin_amdgcn_rsqf(d2);
                float t  = fmaxf(RADIUS - d2*rinv, 0.f);
                float cf = (Li + elem(LB,c)) * (t*t) * rinv;
                ax1 = fmaf(cf, dx, ax1); ay1 = fmaf(cf, dy, ay1); az1 = fmaf(cf, dz, az1);
            }
        }
    }
    float ax = ax0+ax1, ay = ay0+ay1, az = az0+az1;
    for (int off = 32; off > 0; off >>= 1) {
        ax += __shfl_down(ax, off); ay += __shfl_down(ay, off); az += __shfl_down(az, off);
    }
    if (lane == 0) {
        float nx = xi+ax, ny = yi+ay, nz = zi+az;
        store_dc(&qx[i], nx); store_dc(&qy[i], ny); store_dc(&qz[i], nz);
        if (out_pred) {
            out_pred[3*i+0] = nx; out_pred[3*i+1] = ny; out_pred[3*i+2] = nz;
            store_dc(&vnx[i], (nx - locs[3*i+0]) * (1.0f/DT));
            store_dc(&vny[i], (ny - locs[3*i+1]) * (1.0f/DT));
            store_dc(&vnz[i], (nz - locs[3*i+2]) * (1.0f/DT));
        }
    }
}

// ---------------- single fused kernel ----------------
// 256 blocks x 1024 threads (16 waves), 1 particle/wave, 64 KB static LDS.
// 1 block/CU (grid-limited) -> 16 waves/CU = 4 waves/SIMD for latency hiding.

__global__ __launch_bounds__(1024, 4) void k_fused(const float4* __restrict__ locs4,
                                                   const float4* __restrict__ vel4,
                                                   const float* __restrict__ locs,
                                                   float* __restrict__ px, float* __restrict__ py,
                                                   float* __restrict__ pz,
                                                   float* __restrict__ lam,
                                                   float* __restrict__ vnx, float* __restrict__ vny,
                                                   float* __restrict__ vnz,
                                                   float* __restrict__ out,
                                                   unsigned int* __restrict__ bar_ws, int n) {
    __shared__ float4 sx[N4], sy[N4], sz[N4], sl[N4];   // 64 KB
    const int n4   = n >> 2;
    const int lane = threadIdx.x & 63;
    const int wave = threadIdx.x >> 6;
    const int i    = blockIdx.x * 16 + wave;
    const unsigned int ngroups = (unsigned)gridDim.x >> 4;   // 16 blocks per group
    unsigned int phase = 0;

    // predict: every block builds the full predicted-position copy in LDS.
    predict_to_lds(locs4, vel4, sx, sy, sz, n4, threadIdx.x, NTHREADS);
    __syncthreads();

    for (int it = 0; it < 3; ++it) {
        const bool last = (it == 2);

        // rho: LDS pred -> L[i] (global, device-coherent)
        rho_body1(sx, sy, sz, lam, n4, i, lane);
        grid_barrier(bar_ws, ++phase, ngroups);

        // stage L into LDS
        for (int idx = threadIdx.x; idx < n4; idx += NTHREADS) sl[idx] = ((const float4*)lam)[idx];
        __syncthreads();

        // delta: LDS pred + LDS L -> new pred for own particle (global SoA);
        // on last iteration also emit out_pred and new_vel.
        delta_body1(sx, sy, sz, sl, px, py, pz,
                    last ? locs : nullptr, last ? out : nullptr, vnx, vny, vnz,
                    n4, i, lane);
        grid_barrier(bar_ws, ++phase, ngroups);

        // re-stage updated pred into LDS (used by next rho, or by visc)
        for (int idx = threadIdx.x; idx < n4; idx += NTHREADS) {
            sx[idx] = ((const float4*)px)[idx];
            sy[idx] = ((const float4*)py)[idx];
            sz[idx] = ((const float4*)pz)[idx];
        }
        __syncthreads();
    }

    // ---- XSPH viscosity on final positions (pred already in sx/sy/sz) ----
    const float* fpx = (const float*)sx; const float* fpy = (const float*)sy; const float* fpz = (const float*)sz;
    const float xi = fpx[i], yi = fpy[i], zi = fpz[i];
    const float vix = vnx[i], viy = vny[i], viz = vnz[i];   // post-barrier, coherent
    float ws0=0.f, ax0=0.f, ay0=0.f, az0=0.f;
    float ws1=0.f, ax1=0.f, ay1=0.f, az1=0.f;
    const float4* vx4 = (const float4*)vnx;
    const float4* vy4 = (const float4*)vny;
    const float4* vz4 = (const float4*)vnz;
    for (int ch = 0; ch < 4; ++ch) {
        __syncthreads();
        for (int idx = threadIdx.x; idx < CH4; idx += NTHREADS) {
            sl[idx]         = vx4[ch*CH4+idx];
            sl[CH4+idx]     = vy4[ch*CH4+idx];
            sl[2*CH4+idx]   = vz4[ch*CH4+idx];
        }
        __syncthreads();
        for (int k = lane; k < CH4; k += 128) {
            float4 XA = sx[ch*CH4+k],    YA = sy[ch*CH4+k],    ZA = sz[ch*CH4+k];
            float4 VXA = sl[k],          VYA = sl[CH4+k],      VZA = sl[2*CH4+k];
            float4 XB = sx[ch*CH4+k+64], YB = sy[ch*CH4+k+64], ZB = sz[ch*CH4+k+64];
            float4 VXB = sl[k+64],       VYB = sl[CH4+k+64],   VZB = sl[2*CH4+k+64];
#pragma unroll
            for (int c = 0; c < 4; ++c) {
                {
                    float dx = xi-elem(XA,c), dy = yi-elem(YA,c), dz = zi-elem(ZA,c);
                    float d2 = fmaf(dx,dx,EPS); d2 = fmaf(dy,dy,d2); d2 = fmaf(dz,dz,d2);
                    float t  = fmaxf(RADIUS - __builtin_amdgcn_sqrtf(d2), 0.f);
                    float w  = t*t*t;
                    ws0 += w;
                    ax0 = fmaf(w, elem(VXA,c), ax0); ay0 = fmaf(w, elem(VYA,c), ay0); az0 = fmaf(w, elem(VZA,c), az0);
                }
                {
                    float dx = xi-elem(XB,c), dy = yi-elem(YB,c), dz = zi-elem(ZB,c);
                    float d2 = fmaf(dx,dx,EPS); d2 = fmaf(dy,dy,d2); d2 = fmaf(dz,dz,d2);
                    float t  = fmaxf(RADIUS - __builtin_amdgcn_sqrtf(d2), 0.f);
                    float w  = t*t*t;
                    ws1 += w;
                    ax1 = fmaf(w, elem(VXB,c), ax1); ay1 = fmaf(w, elem(VYB,c), ay1); az1 = fmaf(w, elem(VZB,c), az1);
                }
            }
        }
    }
    float sw = ws0+ws1, sax = ax0+ax1, say = ay0+ay1, saz = az0+az1;
    for (int off = 32; off > 0; off >>= 1) {
        sw  += __shfl_down(sw, off);  sax += __shfl_down(sax, off);
        say += __shfl_down(say, off); saz += __shfl_down(saz, off);
    }
    if (lane == 0) {
        constexpr float K = VISCOSITY * DT / DENSITY_REST;
        const float KC = K * SPIKY_C;   // C folded here
        float nvx = vix + KC * (sax - sw * vix);
        float nvy = viy + KC * (say - sw * viy);
        float nvz = viz + KC * (saz - sw * viz);
        float vv = sqrtf(nvx*nvx + nvy*nvy + nvz*nvz);
        float s  = fminf(MAX_VEL / (vv + 1e-4f), 1.0f);
        out[3*n + 3*i + 0] = nvx * s;
        out[3*n + 3*i + 1] = nvy * s;
        out[3*n + 3*i + 2] = nvz * s;
    }
}

extern "C" void kernel_launch(void* const* d_in, const int* in_sizes, int n_in,
                              void* d_out, int out_size, void* d_ws, size_t ws_size,
                              hipStream_t stream) {
    const float* locs = (const float*)d_in[0];
    const float* vel  = (const float*)d_in[1];
    const float4* locs4 = (const float4*)locs;
    const float4* vel4  = (const float4*)vel;
    float* out = (float*)d_out;
    int n = in_sizes[0] / 3;

    float* w = (float*)d_ws;
    float* px  = w;        float* py  = px + n;   float* pz  = py + n;
    float* lam = pz + n;
    float* vnx = lam + n;  float* vny = vnx + n;  float* vnz = vny + n;
    unsigned int* bar_ws = (unsigned int*)(w + 10 * n);   // barrier words after arrays

    int nb = n / 16;   // 16 waves/block, 1 particle/wave -> 256 blocks for n=4096

    // zero the barrier region: ngroups + root + release words, 64B-strided
    int ngroups = nb / 16;
    hipMemsetAsync((void*)bar_ws, 0, (size_t)(ngroups + 2) * 64, stream);

    k_fused<<<dim3(nb), dim3(NTHREADS), 0, stream>>>(locs4, vel4, locs,
                                                     px, py, pz, lam,
                                                     vnx, vny, vnz,
                                                     out, bar_ws, n);
}

// Round 7
// 125.977 us; speedup vs baseline: 1.5821x; 1.1240x over previous
//
#include <hip/hip_runtime.h>
#include <math.h>

#define NMAX  4096
#define NT    1024      // 16 waves/block, 1 particle/wave
#define NC    10        // cells per dim, cell size = RADIUS
#define NCELL 1000

// n assumed == 4096 (reference problem size).

constexpr float RADIUS       = 0.1f;
constexpr float DT           = 1.0f / 60.0f;
constexpr float MAX_VEL      = 3.0f;               // 0.5*0.1/DT
constexpr float VISCOSITY    = 60.0f;
constexpr float DENSITY_REST = 17510.1f;
constexpr float STIFFNESS    = 2.99e-11f;
constexpr float EPS          = 1e-8f;
constexpr float SPIKY_C      = (float)(15.0 / (3.14159265358979323846 * 1e-6)); // 15/(pi*R^6)

#define BAR_STRIDE 16   // uints (64 B) between barrier words

// Device-coherent scalar store: write-through past the non-coherent local L2
// so peer XCDs can see it after the barrier.
__device__ __forceinline__ void store_dc(float* p, float v) {
    __hip_atomic_store(p, v, __ATOMIC_RELAXED, __HIP_MEMORY_SCOPE_AGENT);
}

// Two-level tree grid barrier, monotonic phases (proven R4/R5).
__device__ __forceinline__ void grid_barrier(unsigned int* ws, unsigned int phase,
                                             unsigned int ngroups) {
    __syncthreads();
    if (threadIdx.x == 0) {
        const unsigned g = (unsigned)blockIdx.x >> 4;   // 16 blocks per group
        unsigned a = __hip_atomic_fetch_add(&ws[g * BAR_STRIDE], 1u,
                                            __ATOMIC_RELAXED, __HIP_MEMORY_SCOPE_AGENT);
        if (a == phase * 16u - 1u) {
            unsigned r = __hip_atomic_fetch_add(&ws[ngroups * BAR_STRIDE], 1u,
                                                __ATOMIC_RELAXED, __HIP_MEMORY_SCOPE_AGENT);
            if (r == phase * ngroups - 1u)
                __hip_atomic_store(&ws[(ngroups + 1u) * BAR_STRIDE], phase,
                                   __ATOMIC_RELAXED, __HIP_MEMORY_SCOPE_AGENT);
        }
        while (__hip_atomic_load(&ws[(ngroups + 1u) * BAR_STRIDE], __ATOMIC_RELAXED,
                                 __HIP_MEMORY_SCOPE_AGENT) < phase) {
            __builtin_amdgcn_s_sleep(1);
        }
        __builtin_amdgcn_fence(__ATOMIC_ACQUIRE, "agent");
    }
    __syncthreads();
}

__device__ __forceinline__ int cell_coord(float v) {
    int c = (int)floorf(v * 10.f);
    return min(max(c, 0), NC - 1);
}
__device__ __forceinline__ int cell_id(float x, float y, float z) {
    return (cell_coord(x) * NC + cell_coord(y)) * NC + cell_coord(z);
}

// Per-block counting-sort cell list. Thread t owns particles 4t..4t+3 (passed
// as float4 lanes x,y,z,w). After return: ssx/ssy/ssz hold positions in
// cell-sorted order; ccnt[c] = END offset of cell c (begin(c) = c?ccnt[c-1]:0).
// Returns each owned particle's sorted slot (for later value staging).
__device__ __forceinline__ int4 build_cells(float4 BX, float4 BY, float4 BZ,
                                            float* ssx, float* ssy, float* ssz,
                                            unsigned* ccnt, int tid) {
    ccnt[tid] = 0;            // NT == 1024 covers table + pad
    __syncthreads();
    int c0 = cell_id(BX.x, BY.x, BZ.x);
    int c1 = cell_id(BX.y, BY.y, BZ.y);
    int c2 = cell_id(BX.z, BY.z, BZ.z);
    int c3 = cell_id(BX.w, BY.w, BZ.w);
    atomicAdd(&ccnt[c0], 1u); atomicAdd(&ccnt[c1], 1u);
    atomicAdd(&ccnt[c2], 1u); atomicAdd(&ccnt[c3], 1u);
    __syncthreads();
    if (tid < 64) {           // wave-0 exclusive scan over 1024 entries (in place)
        unsigned carry = 0;
#pragma unroll
        for (int ch = 0; ch < 16; ++ch) {
            int idx = ch * 64 + tid;
            unsigned v = ccnt[idx];
            unsigned incl = v;
            for (int off = 1; off < 64; off <<= 1) {
                unsigned u = __shfl_up(incl, off);
                if (tid >= off) incl += u;
            }
            ccnt[idx] = carry + incl - v;          // exclusive start
            carry += __shfl(incl, 63);
        }
    }
    __syncthreads();
    int4 p;
    p.x = (int)atomicAdd(&ccnt[c0], 1u); ssx[p.x] = BX.x; ssy[p.x] = BY.x; ssz[p.x] = BZ.x;
    p.y = (int)atomicAdd(&ccnt[c1], 1u); ssx[p.y] = BX.y; ssy[p.y] = BY.y; ssz[p.y] = BZ.y;
    p.z = (int)atomicAdd(&ccnt[c2], 1u); ssx[p.z] = BX.z; ssy[p.z] = BY.z; ssz[p.z] = BZ.z;
    p.w = (int)atomicAdd(&ccnt[c3], 1u); ssx[p.w] = BX.w; ssy[p.w] = BY.w; ssz[p.w] = BZ.w;
    __syncthreads();          // ccnt now holds cell END offsets; sorted arrays ready
    return p;
}

// Walk all sorted j in the 27-cell neighborhood of (cix,ciy,ciz): 9 contiguous
// z-runs, lanes splitting each run. body(j) is inlined.
template <typename F>
__device__ __forceinline__ void cell_walk(int cix, int ciy, int ciz,
                                          const unsigned* ccnt, int lane, F&& body) {
    const int zlo = max(ciz - 1, 0), zhi = min(ciz + 1, NC - 1);
#pragma unroll
    for (int dx = -1; dx <= 1; ++dx) {
        int nx = cix + dx;
        if ((unsigned)nx >= (unsigned)NC) continue;
#pragma unroll
        for (int dy = -1; dy <= 1; ++dy) {
            int ny = ciy + dy;
            if ((unsigned)ny >= (unsigned)NC) continue;
            int cb  = (nx * NC + ny) * NC;
            int cA  = cb + zlo, cB = cb + zhi;
            int beg = (cA > 0) ? (int)ccnt[cA - 1] : 0;
            int end = (int)ccnt[cB];
            for (int j = beg + lane; j < end; j += 64) body(j);
        }
    }
}

// ---------------- single fused kernel ----------------
// 256 blocks x 1024 threads (16 waves), 1 particle/wave, ~116 KB static LDS
// -> 1 block/CU, grid 256 = CU count, co-resident (plain launch).

__global__ __launch_bounds__(NT) void k_fused(const float4* __restrict__ locs4,
                                              const float4* __restrict__ vel4,
                                              const float* __restrict__ locs,
                                              const float* __restrict__ vel,
                                              float* __restrict__ px, float* __restrict__ py,
                                              float* __restrict__ pz,
                                              float* __restrict__ lam,
                                              float* __restrict__ vnx, float* __restrict__ vny,
                                              float* __restrict__ vnz,
                                              float* __restrict__ out,
                                              unsigned int* __restrict__ bar_ws, int n) {
    __shared__ float ssx[NMAX], ssy[NMAX], ssz[NMAX];   // 48 KB sorted positions
    __shared__ float ssl[NMAX];                         // 16 KB sorted L
    __shared__ float svx[NMAX], svy[NMAX], svz[NMAX];   // 48 KB sorted new_vel (visc)
    __shared__ unsigned ccnt[NT];                       // 4 KB cell table (+pad)

    const int tid  = threadIdx.x;
    const int lane = tid & 63;
    const int wave = tid >> 6;
    const int i    = blockIdx.x * 16 + wave;            // owned particle (original idx)
    const unsigned ngroups = (unsigned)gridDim.x >> 4;
    unsigned phase = 0;
    (void)n;

    // ---- predict (registers) for this thread's 4 particles; build cell list 1 ----
    float4 BX, BY, BZ;
    {
        float lo[12], ve[12];
        *(float4*)&lo[0] = locs4[3*tid];   *(float4*)&lo[4] = locs4[3*tid+1]; *(float4*)&lo[8] = locs4[3*tid+2];
        *(float4*)&ve[0] = vel4[3*tid];    *(float4*)&ve[4] = vel4[3*tid+1];  *(float4*)&ve[8] = vel4[3*tid+2];
        float P[12];
#pragma unroll
        for (int q = 0; q < 4; ++q) {
            float vx = ve[3*q], vy = ve[3*q+1] - 9.8f * DT, vz = ve[3*q+2];
            float vv = sqrtf(vx*vx + vy*vy + vz*vz);
            float s  = fminf(MAX_VEL / (vv + 1e-4f), 1.0f);
            P[3*q]   = lo[3*q]   + DT * vx * s;
            P[3*q+1] = lo[3*q+1] + DT * vy * s;
            P[3*q+2] = lo[3*q+2] + DT * vz * s;
        }
        BX = make_float4(P[0], P[3], P[6], P[9]);
        BY = make_float4(P[1], P[4], P[7], P[10]);
        BZ = make_float4(P[2], P[5], P[8], P[11]);
    }
    int4 p = build_cells(BX, BY, BZ, ssx, ssy, ssz, ccnt, tid);

    // own predicted position (identical expression tree -> identical rounding)
    float xi, yi, zi;
    {
        float vx = vel[3*i], vy = vel[3*i+1] - 9.8f * DT, vz = vel[3*i+2];
        float vv = sqrtf(vx*vx + vy*vy + vz*vz);
        float s  = fminf(MAX_VEL / (vv + 1e-4f), 1.0f);
        xi = locs[3*i]   + DT * vx * s;
        yi = locs[3*i+1] + DT * vy * s;
        zi = locs[3*i+2] + DT * vz * s;
    }

    for (int it = 0; it < 3; ++it) {
        const bool last = (it == 2);
        const int cix = cell_coord(xi), ciy = cell_coord(yi), ciz = cell_coord(zi);

        // ---- rho: neighbor-cell walk over sorted positions ----
        float S = 0.f;
        cell_walk(cix, ciy, ciz, ccnt, lane, [&](int j) {
            float ddx = xi - ssx[j], ddy = yi - ssy[j], ddz = zi - ssz[j];
            float d2 = fmaf(ddx,ddx,EPS); d2 = fmaf(ddy,ddy,d2); d2 = fmaf(ddz,ddz,d2);
            float t  = fmaxf(RADIUS - __builtin_amdgcn_sqrtf(d2), 0.f);
            S = fmaf(t*t, t, S);
        });
        for (int off = 32; off > 0; off >>= 1) S += __shfl_down(S, off);
        if (lane == 0) {
            const float ts  = RADIUS - __builtin_amdgcn_sqrtf(EPS);  // exact self-term
            const float TS3 = ts*ts*ts;
            const float k3  = 3.f * SPIKY_C * STIFFNESS;             // L = -3C*lam
            store_dc(&lam[i], k3 * (SPIKY_C * (S - TS3) - DENSITY_REST));
        }
        grid_barrier(bar_ws, ++phase, ngroups);

        // ---- stage L into sorted order via remembered slots ----
        {
            float4 l4 = ((const float4*)lam)[tid];
            ssl[p.x] = l4.x; ssl[p.y] = l4.y; ssl[p.z] = l4.z; ssl[p.w] = l4.w;
        }
        float Li = lam[i];
        __syncthreads();

        // ---- delta: neighbor-cell walk ----
        float ax = 0.f, ay = 0.f, az = 0.f;
        cell_walk(cix, ciy, ciz, ccnt, lane, [&](int j) {
            float ddx = xi - ssx[j], ddy = yi - ssy[j], ddz = zi - ssz[j];
            float d2 = fmaf(ddx,ddx,EPS); d2 = fmaf(ddy,ddy,d2); d2 = fmaf(ddz,ddz,d2);
            float rinv = __builtin_amdgcn_rsqf(d2);
            float t  = fmaxf(RADIUS - d2*rinv, 0.f);
            float cf = (Li + ssl[j]) * (t*t) * rinv;
            ax = fmaf(cf, ddx, ax); ay = fmaf(cf, ddy, ay); az = fmaf(cf, ddz, az);
        });
        for (int off = 32; off > 0; off >>= 1) {
            ax += __shfl_down(ax, off); ay += __shfl_down(ay, off); az += __shfl_down(az, off);
        }
        if (lane == 0) {
            float nx = xi + ax, ny = yi + ay, nz = zi + az;
            store_dc(&px[i], nx); store_dc(&py[i], ny); store_dc(&pz[i], nz);
            if (last) {
                out[3*i+0] = nx; out[3*i+1] = ny; out[3*i+2] = nz;
                store_dc(&vnx[i], (nx - locs[3*i+0]) * (1.0f/DT));
                store_dc(&vny[i], (ny - locs[3*i+1]) * (1.0f/DT));
                store_dc(&vnz[i], (nz - locs[3*i+2]) * (1.0f/DT));
            }
        }
        grid_barrier(bar_ws, ++phase, ngroups);

        // ---- rebuild cell list from updated pred (final build also serves visc) ----
        BX = ((const float4*)px)[tid];
        BY = ((const float4*)py)[tid];
        BZ = ((const float4*)pz)[tid];
        p  = build_cells(BX, BY, BZ, ssx, ssy, ssz, ccnt, tid);
        xi = px[i]; yi = py[i]; zi = pz[i];
    }

    // ---- XSPH viscosity: stage new_vel sorted, then neighbor-cell walk ----
    {
        float4 a4 = ((const float4*)vnx)[tid];
        float4 b4 = ((const float4*)vny)[tid];
        float4 c4 = ((const float4*)vnz)[tid];
        svx[p.x] = a4.x; svx[p.y] = a4.y; svx[p.z] = a4.z; svx[p.w] = a4.w;
        svy[p.x] = b4.x; svy[p.y] = b4.y; svy[p.z] = b4.z; svy[p.w] = b4.w;
        svz[p.x] = c4.x; svz[p.y] = c4.y; svz[p.z] = c4.z; svz[p.w] = c4.w;
    }
    const float vix = vnx[i], viy = vny[i], viz = vnz[i];
    __syncthreads();

    const int cix = cell_coord(xi), ciy = cell_coord(yi), ciz = cell_coord(zi);
    float sw = 0.f, sax = 0.f, say = 0.f, saz = 0.f;
    cell_walk(cix, ciy, ciz, ccnt, lane, [&](int j) {
        float ddx = xi - ssx[j], ddy = yi - ssy[j], ddz = zi - ssz[j];
        float d2 = fmaf(ddx,ddx,EPS); d2 = fmaf(ddy,ddy,d2); d2 = fmaf(ddz,ddz,d2);
        float t  = fmaxf(RADIUS - __builtin_amdgcn_sqrtf(d2), 0.f);
        float w  = t*t*t;
        sw += w;
        sax = fmaf(w, svx[j], sax); say = fmaf(w, svy[j], say); saz = fmaf(w, svz[j], saz);
    });
    for (int off = 32; off > 0; off >>= 1) {
        sw  += __shfl_down(sw, off);  sax += __shfl_down(sax, off);
        say += __shfl_down(say, off); saz += __shfl_down(saz, off);
    }
    if (lane == 0) {
        constexpr float K = VISCOSITY * DT / DENSITY_REST;
        const float KC = K * SPIKY_C;   // C folded here; self-term cancels exactly
        float nvx = vix + KC * (sax - sw * vix);
        float nvy = viy + KC * (say - sw * viy);
        float nvz = viz + KC * (saz - sw * viz);
        float vv = sqrtf(nvx*nvx + nvy*nvy + nvz*nvz);
        float s  = fminf(MAX_VEL / (vv + 1e-4f), 1.0f);
        out[3*NMAX + 3*i + 0] = nvx * s;
        out[3*NMAX + 3*i + 1] = nvy * s;
        out[3*NMAX + 3*i + 2] = nvz * s;
    }
}

extern "C" void kernel_launch(void* const* d_in, const int* in_sizes, int n_in,
                              void* d_out, int out_size, void* d_ws, size_t ws_size,
                              hipStream_t stream) {
    const float* locs = (const float*)d_in[0];
    const float* vel  = (const float*)d_in[1];
    const float4* locs4 = (const float4*)locs;
    const float4* vel4  = (const float4*)vel;
    float* out = (float*)d_out;
    int n = in_sizes[0] / 3;   // 4096

    float* w = (float*)d_ws;
    float* px  = w;        float* py  = px + n;   float* pz  = py + n;
    float* lam = pz + n;
    float* vnx = lam + n;  float* vny = vnx + n;  float* vnz = vny + n;
    unsigned int* bar_ws = (unsigned int*)(w + 10 * n);

    int nb = n / 16;   // 16 waves/block, 1 particle/wave -> 256 blocks

    // zero barrier region: ngroups + root + release words, 64B-strided
    int ngroups = nb / 16;
    (void)hipMemsetAsync((void*)bar_ws, 0, (size_t)(ngroups + 2) * 64, stream);

    k_fused<<<dim3(nb), dim3(NT), 0, stream>>>(locs4, vel4, locs, vel,
                                               px, py, pz, lam,
                                               vnx, vny, vnz,
                                               out, bar_ws, n);
}

// Round 8
// 119.951 us; speedup vs baseline: 1.6616x; 1.0502x over previous
//
#include <hip/hip_runtime.h>
#include <math.h>

#define NMAX  4096
#define NT    1024      // 16 waves/block, 1 particle/wave
#define NC    10        // cells per dim, cell size = RADIUS
#define NCELL 1000

// n assumed == 4096 (reference problem size).

constexpr float RADIUS       = 0.1f;
constexpr float DT           = 1.0f / 60.0f;
constexpr float MAX_VEL      = 3.0f;               // 0.5*0.1/DT
constexpr float VISCOSITY    = 60.0f;
constexpr float DENSITY_REST = 17510.1f;
constexpr float STIFFNESS    = 2.99e-11f;
constexpr float EPS          = 1e-8f;
constexpr float SPIKY_C      = (float)(15.0 / (3.14159265358979323846 * 1e-6)); // 15/(pi*R^6)

#define BAR_STRIDE 16   // uints (64 B) between barrier words

// Device-coherent scalar store: write-through past the non-coherent local L2
// so peer XCDs can see it after the barrier.
__device__ __forceinline__ void store_dc(float* p, float v) {
    __hip_atomic_store(p, v, __ATOMIC_RELAXED, __HIP_MEMORY_SCOPE_AGENT);
}

// Two-level tree grid barrier, monotonic phases (proven R4-R7).
__device__ __forceinline__ void grid_barrier(unsigned int* ws, unsigned int phase,
                                             unsigned int ngroups) {
    __syncthreads();
    if (threadIdx.x == 0) {
        const unsigned g = (unsigned)blockIdx.x >> 4;   // 16 blocks per group
        unsigned a = __hip_atomic_fetch_add(&ws[g * BAR_STRIDE], 1u,
                                            __ATOMIC_RELAXED, __HIP_MEMORY_SCOPE_AGENT);
        if (a == phase * 16u - 1u) {
            unsigned r = __hip_atomic_fetch_add(&ws[ngroups * BAR_STRIDE], 1u,
                                                __ATOMIC_RELAXED, __HIP_MEMORY_SCOPE_AGENT);
            if (r == phase * ngroups - 1u)
                __hip_atomic_store(&ws[(ngroups + 1u) * BAR_STRIDE], phase,
                                   __ATOMIC_RELAXED, __HIP_MEMORY_SCOPE_AGENT);
        }
        while (__hip_atomic_load(&ws[(ngroups + 1u) * BAR_STRIDE], __ATOMIC_RELAXED,
                                 __HIP_MEMORY_SCOPE_AGENT) < phase) {
            __builtin_amdgcn_s_sleep(1);
        }
        __builtin_amdgcn_fence(__ATOMIC_ACQUIRE, "agent");
    }
    __syncthreads();
}

__device__ __forceinline__ int cell_coord(float v) {
    int c = (int)floorf(v * 10.f);
    return min(max(c, 0), NC - 1);
}
__device__ __forceinline__ int cell_id(float x, float y, float z) {
    return (cell_coord(x) * NC + cell_coord(y)) * NC + cell_coord(z);
}

// Per-block counting-sort cell list (AoS float4, parallel scan).
// Thread t owns particles 4t..4t+3 (float4 lanes). After return: ssp[slot] =
// (x,y,z,0) in cell-sorted order; ccnt[c] = END offset of cell c
// (begin(c) = c ? ccnt[c-1] : 0). Returns each owned particle's sorted slot.
__device__ __forceinline__ int4 build_cells(float4 BX, float4 BY, float4 BZ,
                                            float4* ssp, unsigned* ccnt,
                                            unsigned* wtot, int tid) {
    ccnt[tid] = 0;
    __syncthreads();
    int c0 = cell_id(BX.x, BY.x, BZ.x);
    int c1 = cell_id(BX.y, BY.y, BZ.y);
    int c2 = cell_id(BX.z, BY.z, BZ.z);
    int c3 = cell_id(BX.w, BY.w, BZ.w);
    atomicAdd(&ccnt[c0], 1u); atomicAdd(&ccnt[c1], 1u);
    atomicAdd(&ccnt[c2], 1u); atomicAdd(&ccnt[c3], 1u);
    __syncthreads();
    // all-wave parallel exclusive scan over 1024 entries: thread t = entry t
    {
        const int l = tid & 63, w = tid >> 6;
        unsigned v = ccnt[tid];
        unsigned incl = v;
        for (int off = 1; off < 64; off <<= 1) {
            unsigned u = __shfl_up(incl, off);
            if (l >= off) incl += u;
        }
        if (l == 63) wtot[w] = incl;        // per-wave total
        unsigned excl = incl - v;
        __syncthreads();
        if (tid < 16) {                     // exclusive scan of 16 wave totals
            unsigned tv = wtot[tid];
            unsigned ti = tv;
            for (int off = 1; off < 16; off <<= 1) {
                unsigned u = __shfl_up(ti, off);
                if (tid >= off) ti += u;
            }
            wtot[tid] = ti - tv;
        }
        __syncthreads();
        ccnt[tid] = excl + wtot[w];         // global exclusive start
    }
    __syncthreads();
    int4 p;
    p.x = (int)atomicAdd(&ccnt[c0], 1u); ssp[p.x] = make_float4(BX.x, BY.x, BZ.x, 0.f);
    p.y = (int)atomicAdd(&ccnt[c1], 1u); ssp[p.y] = make_float4(BX.y, BY.y, BZ.y, 0.f);
    p.z = (int)atomicAdd(&ccnt[c2], 1u); ssp[p.z] = make_float4(BX.z, BY.z, BZ.z, 0.f);
    p.w = (int)atomicAdd(&ccnt[c3], 1u); ssp[p.w] = make_float4(BX.w, BY.w, BZ.w, 0.f);
    __syncthreads();          // ccnt now holds cell END offsets; sorted array ready
    return p;
}

// Walk all sorted j in the 27-cell neighborhood of (cix,ciy,ciz): 9 contiguous
// z-runs, lanes splitting each run. body(j) is inlined.
template <typename F>
__device__ __forceinline__ void cell_walk(int cix, int ciy, int ciz,
                                          const unsigned* ccnt, int lane, F&& body) {
    const int zlo = max(ciz - 1, 0), zhi = min(ciz + 1, NC - 1);
#pragma unroll
    for (int dx = -1; dx <= 1; ++dx) {
        int nx = cix + dx;
        if ((unsigned)nx >= (unsigned)NC) continue;
#pragma unroll
        for (int dy = -1; dy <= 1; ++dy) {
            int ny = ciy + dy;
            if ((unsigned)ny >= (unsigned)NC) continue;
            int cb  = (nx * NC + ny) * NC;
            int cA  = cb + zlo, cB = cb + zhi;
            int beg = (cA > 0) ? (int)ccnt[cA - 1] : 0;
            int end = (int)ccnt[cB];
            for (int j = beg + lane; j < end; j += 64) body(j);
        }
    }
}

// ---------------- single fused kernel ----------------
// 256 blocks x 1024 threads (16 waves), 1 particle/wave, ~132 KB static LDS
// -> 1 block/CU, grid 256 = CU count, co-resident (plain launch).

__global__ __launch_bounds__(NT) void k_fused(const float4* __restrict__ locs4,
                                              const float4* __restrict__ vel4,
                                              const float* __restrict__ locs,
                                              const float* __restrict__ vel,
                                              float* __restrict__ px, float* __restrict__ py,
                                              float* __restrict__ pz,
                                              float* __restrict__ lam,
                                              float* __restrict__ vnx, float* __restrict__ vny,
                                              float* __restrict__ vnz,
                                              float* __restrict__ out,
                                              unsigned int* __restrict__ bar_ws, int n) {
    __shared__ float4 ssp[NMAX];        // 64 KB sorted (x,y,z,lam)
    __shared__ float4 svp[NMAX];        // 64 KB sorted (vx,vy,vz,0) for visc
    __shared__ unsigned ccnt[NT];       // 4 KB cell table (+pad)
    __shared__ unsigned wtot[16];       // wave totals for scan

    const int tid  = threadIdx.x;
    const int lane = tid & 63;
    const int wave = tid >> 6;
    const int i    = blockIdx.x * 16 + wave;            // owned particle (original idx)
    const unsigned ngroups = (unsigned)gridDim.x >> 4;
    unsigned phase = 0;
    (void)n;

    // ---- predict (registers) for this thread's 4 particles; build cell list 1 ----
    float4 BX, BY, BZ;
    {
        float lo[12], ve[12];
        *(float4*)&lo[0] = locs4[3*tid];   *(float4*)&lo[4] = locs4[3*tid+1]; *(float4*)&lo[8] = locs4[3*tid+2];
        *(float4*)&ve[0] = vel4[3*tid];    *(float4*)&ve[4] = vel4[3*tid+1];  *(float4*)&ve[8] = vel4[3*tid+2];
        float P[12];
#pragma unroll
        for (int q = 0; q < 4; ++q) {
            float vx = ve[3*q], vy = ve[3*q+1] - 9.8f * DT, vz = ve[3*q+2];
            float vv = sqrtf(vx*vx + vy*vy + vz*vz);
            float s  = fminf(MAX_VEL / (vv + 1e-4f), 1.0f);
            P[3*q]   = lo[3*q]   + DT * vx * s;
            P[3*q+1] = lo[3*q+1] + DT * vy * s;
            P[3*q+2] = lo[3*q+2] + DT * vz * s;
        }
        BX = make_float4(P[0], P[3], P[6], P[9]);
        BY = make_float4(P[1], P[4], P[7], P[10]);
        BZ = make_float4(P[2], P[5], P[8], P[11]);
    }
    int4 p = build_cells(BX, BY, BZ, ssp, ccnt, wtot, tid);

    // own predicted position (identical expression tree -> identical rounding)
    float xi, yi, zi;
    {
        float vx = vel[3*i], vy = vel[3*i+1] - 9.8f * DT, vz = vel[3*i+2];
        float vv = sqrtf(vx*vx + vy*vy + vz*vz);
        float s  = fminf(MAX_VEL / (vv + 1e-4f), 1.0f);
        xi = locs[3*i]   + DT * vx * s;
        yi = locs[3*i+1] + DT * vy * s;
        zi = locs[3*i+2] + DT * vz * s;
    }

    for (int it = 0; it < 3; ++it) {
        const bool last = (it == 2);
        const int cix = cell_coord(xi), ciy = cell_coord(yi), ciz = cell_coord(zi);

        // ---- rho: neighbor-cell walk (1 x b128 load per candidate) ----
        float S = 0.f;
        cell_walk(cix, ciy, ciz, ccnt, lane, [&](int j) {
            float4 P = ssp[j];
            float ddx = xi - P.x, ddy = yi - P.y, ddz = zi - P.z;
            float d2 = fmaf(ddx,ddx,EPS); d2 = fmaf(ddy,ddy,d2); d2 = fmaf(ddz,ddz,d2);
            float t  = fmaxf(RADIUS - __builtin_amdgcn_sqrtf(d2), 0.f);
            S = fmaf(t*t, t, S);
        });
        for (int off = 32; off > 0; off >>= 1) S += __shfl_down(S, off);
        if (lane == 0) {
            const float ts  = RADIUS - __builtin_amdgcn_sqrtf(EPS);  // exact self-term
            const float TS3 = ts*ts*ts;
            const float k3  = 3.f * SPIKY_C * STIFFNESS;             // L = -3C*lam
            store_dc(&lam[i], k3 * (SPIKY_C * (S - TS3) - DENSITY_REST));
        }
        grid_barrier(bar_ws, ++phase, ngroups);

        // ---- stage L into .w of sorted slots ----
        {
            float4 l4 = ((const float4*)lam)[tid];
            ssp[p.x].w = l4.x; ssp[p.y].w = l4.y; ssp[p.z].w = l4.z; ssp[p.w].w = l4.w;
        }
        float Li = lam[i];
        __syncthreads();

        // ---- delta: neighbor-cell walk (x,y,z,L in one b128) ----
        float ax = 0.f, ay = 0.f, az = 0.f;
        cell_walk(cix, ciy, ciz, ccnt, lane, [&](int j) {
            float4 P = ssp[j];
            float ddx = xi - P.x, ddy = yi - P.y, ddz = zi - P.z;
            float d2 = fmaf(ddx,ddx,EPS); d2 = fmaf(ddy,ddy,d2); d2 = fmaf(ddz,ddz,d2);
            float rinv = __builtin_amdgcn_rsqf(d2);
            float t  = fmaxf(RADIUS - d2*rinv, 0.f);
            float cf = (Li + P.w) * (t*t) * rinv;
            ax = fmaf(cf, ddx, ax); ay = fmaf(cf, ddy, ay); az = fmaf(cf, ddz, az);
        });
        for (int off = 32; off > 0; off >>= 1) {
            ax += __shfl_down(ax, off); ay += __shfl_down(ay, off); az += __shfl_down(az, off);
        }
        if (lane == 0) {
            float nx = xi + ax, ny = yi + ay, nz = zi + az;
            store_dc(&px[i], nx); store_dc(&py[i], ny); store_dc(&pz[i], nz);
            if (last) {
                out[3*i+0] = nx; out[3*i+1] = ny; out[3*i+2] = nz;
                store_dc(&vnx[i], (nx - locs[3*i+0]) * (1.0f/DT));
                store_dc(&vny[i], (ny - locs[3*i+1]) * (1.0f/DT));
                store_dc(&vnz[i], (nz - locs[3*i+2]) * (1.0f/DT));
            }
        }
        grid_barrier(bar_ws, ++phase, ngroups);

        // ---- rebuild cell list from updated pred (final build also serves visc) ----
        BX = ((const float4*)px)[tid];
        BY = ((const float4*)py)[tid];
        BZ = ((const float4*)pz)[tid];
        p  = build_cells(BX, BY, BZ, ssp, ccnt, wtot, tid);
        xi = px[i]; yi = py[i]; zi = pz[i];
    }

    // ---- XSPH viscosity: stage new_vel sorted (AoS), then neighbor-cell walk ----
    {
        float4 a4 = ((const float4*)vnx)[tid];
        float4 b4 = ((const float4*)vny)[tid];
        float4 c4 = ((const float4*)vnz)[tid];
        svp[p.x] = make_float4(a4.x, b4.x, c4.x, 0.f);
        svp[p.y] = make_float4(a4.y, b4.y, c4.y, 0.f);
        svp[p.z] = make_float4(a4.z, b4.z, c4.z, 0.f);
        svp[p.w] = make_float4(a4.w, b4.w, c4.w, 0.f);
    }
    const float vix = vnx[i], viy = vny[i], viz = vnz[i];
    __syncthreads();

    const int cix = cell_coord(xi), ciy = cell_coord(yi), ciz = cell_coord(zi);
    float sw = 0.f, sax = 0.f, say = 0.f, saz = 0.f;
    cell_walk(cix, ciy, ciz, ccnt, lane, [&](int j) {
        float4 P = ssp[j];
        float4 V = svp[j];
        float ddx = xi - P.x, ddy = yi - P.y, ddz = zi - P.z;
        float d2 = fmaf(ddx,ddx,EPS); d2 = fmaf(ddy,ddy,d2); d2 = fmaf(ddz,ddz,d2);
        float t  = fmaxf(RADIUS - __builtin_amdgcn_sqrtf(d2), 0.f);
        float w  = t*t*t;
        sw += w;
        sax = fmaf(w, V.x, sax); say = fmaf(w, V.y, say); saz = fmaf(w, V.z, saz);
    });
    for (int off = 32; off > 0; off >>= 1) {
        sw  += __shfl_down(sw, off);  sax += __shfl_down(sax, off);
        say += __shfl_down(say, off); saz += __shfl_down(saz, off);
    }
    if (lane == 0) {
        constexpr float K = VISCOSITY * DT / DENSITY_REST;
        const float KC = K * SPIKY_C;   // C folded here; self-term cancels exactly
        float nvx = vix + KC * (sax - sw * vix);
        float nvy = viy + KC * (say - sw * viy);
        float nvz = viz + KC * (saz - sw * viz);
        float vv = sqrtf(nvx*nvx + nvy*nvy + nvz*nvz);
        float s  = fminf(MAX_VEL / (vv + 1e-4f), 1.0f);
        out[3*NMAX + 3*i + 0] = nvx * s;
        out[3*NMAX + 3*i + 1] = nvy * s;
        out[3*NMAX + 3*i + 2] = nvz * s;
    }
}

extern "C" void kernel_launch(void* const* d_in, const int* in_sizes, int n_in,
                              void* d_out, int out_size, void* d_ws, size_t ws_size,
                              hipStream_t stream) {
    const float* locs = (const float*)d_in[0];
    const float* vel  = (const float*)d_in[1];
    const float4* locs4 = (const float4*)locs;
    const float4* vel4  = (const float4*)vel;
    float* out = (float*)d_out;
    int n = in_sizes[0] / 3;   // 4096

    float* w = (float*)d_ws;
    float* px  = w;        float* py  = px + n;   float* pz  = py + n;
    float* lam = pz + n;
    float* vnx = lam + n;  float* vny = vnx + n;  float* vnz = vny + n;
    unsigned int* bar_ws = (unsigned int*)(w + 10 * n);

    int nb = n / 16;   // 16 waves/block, 1 particle/wave -> 256 blocks

    // zero barrier region: ngroups + root + release words, 64B-strided
    int ngroups = nb / 16;
    (void)hipMemsetAsync((void*)bar_ws, 0, (size_t)(ngroups + 2) * 64, stream);

    k_fused<<<dim3(nb), dim3(NT), 0, stream>>>(locs4, vel4, locs, vel,
                                               px, py, pz, lam,
                                               vnx, vny, vnz,
                                               out, bar_ws, n);
}

// Round 9
// 111.405 us; speedup vs baseline: 1.7890x; 1.0767x over previous
//
#include <hip/hip_runtime.h>
#include <math.h>

#define NMAX  4096
#define NT    1024      // 16 waves/block, 1 particle/wave
#define NC    10        // cells per dim, cell size = RADIUS
#define NCELL 1000

// n assumed == 4096 (reference problem size).

constexpr float RADIUS       = 0.1f;
constexpr float DT           = 1.0f / 60.0f;
constexpr float MAX_VEL      = 3.0f;               // 0.5*0.1/DT
constexpr float VISCOSITY    = 60.0f;
constexpr float DENSITY_REST = 17510.1f;
constexpr float STIFFNESS    = 2.99e-11f;
constexpr float EPS          = 1e-8f;
constexpr float SPIKY_C      = (float)(15.0 / (3.14159265358979323846 * 1e-6)); // 15/(pi*R^6)

#define BAR_STRIDE 16   // uints (64 B) between barrier words

// Device-coherent scalar store: write-through past the non-coherent local L2
// so peer XCDs can see it after the barrier.
__device__ __forceinline__ void store_dc(float* p, float v) {
    __hip_atomic_store(p, v, __ATOMIC_RELAXED, __HIP_MEMORY_SCOPE_AGENT);
}

// Device-coherent loads: agent-scope relaxed atomics compile to sc1 loads that
// bypass the (possibly stale) L1/L2 and read the coherence point directly.
// This replaces the acquire fence (whole-L2 invalidate) in the barrier.
__device__ __forceinline__ float load_dc(const float* p) {
    return __hip_atomic_load(p, __ATOMIC_RELAXED, __HIP_MEMORY_SCOPE_AGENT);
}
__device__ __forceinline__ float4 load_dc4(const float4* p) {
    const unsigned long long* q = (const unsigned long long*)p;
    unsigned long long a = __hip_atomic_load(q,     __ATOMIC_RELAXED, __HIP_MEMORY_SCOPE_AGENT);
    unsigned long long b = __hip_atomic_load(q + 1, __ATOMIC_RELAXED, __HIP_MEMORY_SCOPE_AGENT);
    float4 r;
    ((unsigned long long*)&r)[0] = a;
    ((unsigned long long*)&r)[1] = b;
    return r;
}

// Two-level tree grid barrier, monotonic phases. NO acquire fence: all
// cross-block data is read via load_dc/load_dc4 (sc1, coherence-point reads),
// so no cache invalidation is needed. __syncthreads before arrival drains
// each wave's vmcnt, so prior sc1 data stores are at the coherence point
// before the flag RMW; flag observed => data visible to sc1 loads.
__device__ __forceinline__ void grid_barrier(unsigned int* ws, unsigned int phase,
                                             unsigned int ngroups) {
    __syncthreads();
    if (threadIdx.x == 0) {
        const unsigned g = (unsigned)blockIdx.x >> 4;   // 16 blocks per group
        unsigned a = __hip_atomic_fetch_add(&ws[g * BAR_STRIDE], 1u,
                                            __ATOMIC_RELAXED, __HIP_MEMORY_SCOPE_AGENT);
        if (a == phase * 16u - 1u) {
            unsigned r = __hip_atomic_fetch_add(&ws[ngroups * BAR_STRIDE], 1u,
                                                __ATOMIC_RELAXED, __HIP_MEMORY_SCOPE_AGENT);
            if (r == phase * ngroups - 1u)
                __hip_atomic_store(&ws[(ngroups + 1u) * BAR_STRIDE], phase,
                                   __ATOMIC_RELAXED, __HIP_MEMORY_SCOPE_AGENT);
        }
        while (__hip_atomic_load(&ws[(ngroups + 1u) * BAR_STRIDE], __ATOMIC_RELAXED,
                                 __HIP_MEMORY_SCOPE_AGENT) < phase) {
            __builtin_amdgcn_s_sleep(1);
        }
    }
    __syncthreads();
}

__device__ __forceinline__ int cell_coord(float v) {
    int c = (int)floorf(v * 10.f);
    return min(max(c, 0), NC - 1);
}
__device__ __forceinline__ int cell_id(float x, float y, float z) {
    return (cell_coord(x) * NC + cell_coord(y)) * NC + cell_coord(z);
}

// Per-block counting-sort cell list (AoS float4, parallel scan).
__device__ __forceinline__ int4 build_cells(float4 BX, float4 BY, float4 BZ,
                                            float4* ssp, unsigned* ccnt,
                                            unsigned* wtot, int tid) {
    ccnt[tid] = 0;
    __syncthreads();
    int c0 = cell_id(BX.x, BY.x, BZ.x);
    int c1 = cell_id(BX.y, BY.y, BZ.y);
    int c2 = cell_id(BX.z, BY.z, BZ.z);
    int c3 = cell_id(BX.w, BY.w, BZ.w);
    atomicAdd(&ccnt[c0], 1u); atomicAdd(&ccnt[c1], 1u);
    atomicAdd(&ccnt[c2], 1u); atomicAdd(&ccnt[c3], 1u);
    __syncthreads();
    // all-wave parallel exclusive scan over 1024 entries: thread t = entry t
    {
        const int l = tid & 63, w = tid >> 6;
        unsigned v = ccnt[tid];
        unsigned incl = v;
        for (int off = 1; off < 64; off <<= 1) {
            unsigned u = __shfl_up(incl, off);
            if (l >= off) incl += u;
        }
        if (l == 63) wtot[w] = incl;        // per-wave total
        unsigned excl = incl - v;
        __syncthreads();
        if (tid < 16) {                     // exclusive scan of 16 wave totals
            unsigned tv = wtot[tid];
            unsigned ti = tv;
            for (int off = 1; off < 16; off <<= 1) {
                unsigned u = __shfl_up(ti, off);
                if (tid >= off) ti += u;
            }
            wtot[tid] = ti - tv;
        }
        __syncthreads();
        ccnt[tid] = excl + wtot[w];         // global exclusive start
    }
    __syncthreads();
    int4 p;
    p.x = (int)atomicAdd(&ccnt[c0], 1u); ssp[p.x] = make_float4(BX.x, BY.x, BZ.x, 0.f);
    p.y = (int)atomicAdd(&ccnt[c1], 1u); ssp[p.y] = make_float4(BX.y, BY.y, BZ.y, 0.f);
    p.z = (int)atomicAdd(&ccnt[c2], 1u); ssp[p.z] = make_float4(BX.z, BY.z, BZ.z, 0.f);
    p.w = (int)atomicAdd(&ccnt[c3], 1u); ssp[p.w] = make_float4(BX.w, BY.w, BZ.w, 0.f);
    __syncthreads();          // ccnt now holds cell END offsets; sorted array ready
    return p;
}

// Walk all sorted j in the 27-cell neighborhood of (cix,ciy,ciz): 9 contiguous
// z-runs, lanes splitting each run. body(j) is inlined.
template <typename F>
__device__ __forceinline__ void cell_walk(int cix, int ciy, int ciz,
                                          const unsigned* ccnt, int lane, F&& body) {
    const int zlo = max(ciz - 1, 0), zhi = min(ciz + 1, NC - 1);
#pragma unroll
    for (int dx = -1; dx <= 1; ++dx) {
        int nx = cix + dx;
        if ((unsigned)nx >= (unsigned)NC) continue;
#pragma unroll
        for (int dy = -1; dy <= 1; ++dy) {
            int ny = ciy + dy;
            if ((unsigned)ny >= (unsigned)NC) continue;
            int cb  = (nx * NC + ny) * NC;
            int cA  = cb + zlo, cB = cb + zhi;
            int beg = (cA > 0) ? (int)ccnt[cA - 1] : 0;
            int end = (int)ccnt[cB];
            for (int j = beg + lane; j < end; j += 64) body(j);
        }
    }
}

// ---------------- single fused kernel ----------------
// 256 blocks x 1024 threads (16 waves), 1 particle/wave, ~132 KB static LDS
// -> 1 block/CU, grid 256 = CU count, co-resident (plain launch).

__global__ __launch_bounds__(NT) void k_fused(const float4* __restrict__ locs4,
                                              const float4* __restrict__ vel4,
                                              const float* __restrict__ locs,
                                              const float* __restrict__ vel,
                                              float* __restrict__ px, float* __restrict__ py,
                                              float* __restrict__ pz,
                                              float* __restrict__ lam,
                                              float* __restrict__ vnx, float* __restrict__ vny,
                                              float* __restrict__ vnz,
                                              float* __restrict__ out,
                                              unsigned int* __restrict__ bar_ws, int n) {
    __shared__ float4 ssp[NMAX];        // 64 KB sorted (x,y,z,lam)
    __shared__ float4 svp[NMAX];        // 64 KB sorted (vx,vy,vz,0) for visc
    __shared__ unsigned ccnt[NT];       // 4 KB cell table (+pad)
    __shared__ unsigned wtot[16];       // wave totals for scan

    const int tid  = threadIdx.x;
    const int lane = tid & 63;
    const int wave = tid >> 6;
    const int i    = blockIdx.x * 16 + wave;            // owned particle (original idx)
    const unsigned ngroups = (unsigned)gridDim.x >> 4;
    unsigned phase = 0;
    (void)n;

    // ---- predict (registers) for this thread's 4 particles; build cell list 1 ----
    float4 BX, BY, BZ;
    {
        float lo[12], ve[12];
        *(float4*)&lo[0] = locs4[3*tid];   *(float4*)&lo[4] = locs4[3*tid+1]; *(float4*)&lo[8] = locs4[3*tid+2];
        *(float4*)&ve[0] = vel4[3*tid];    *(float4*)&ve[4] = vel4[3*tid+1];  *(float4*)&ve[8] = vel4[3*tid+2];
        float P[12];
#pragma unroll
        for (int q = 0; q < 4; ++q) {
            float vx = ve[3*q], vy = ve[3*q+1] - 9.8f * DT, vz = ve[3*q+2];
            float vv = sqrtf(vx*vx + vy*vy + vz*vz);
            float s  = fminf(MAX_VEL / (vv + 1e-4f), 1.0f);
            P[3*q]   = lo[3*q]   + DT * vx * s;
            P[3*q+1] = lo[3*q+1] + DT * vy * s;
            P[3*q+2] = lo[3*q+2] + DT * vz * s;
        }
        BX = make_float4(P[0], P[3], P[6], P[9]);
        BY = make_float4(P[1], P[4], P[7], P[10]);
        BZ = make_float4(P[2], P[5], P[8], P[11]);
    }
    int4 p = build_cells(BX, BY, BZ, ssp, ccnt, wtot, tid);

    // own predicted position (identical expression tree -> identical rounding)
    float xi, yi, zi;
    {
        float vx = vel[3*i], vy = vel[3*i+1] - 9.8f * DT, vz = vel[3*i+2];
        float vv = sqrtf(vx*vx + vy*vy + vz*vz);
        float s  = fminf(MAX_VEL / (vv + 1e-4f), 1.0f);
        xi = locs[3*i]   + DT * vx * s;
        yi = locs[3*i+1] + DT * vy * s;
        zi = locs[3*i+2] + DT * vz * s;
    }

    for (int it = 0; it < 3; ++it) {
        const bool last = (it == 2);
        const int cix = cell_coord(xi), ciy = cell_coord(yi), ciz = cell_coord(zi);

        // ---- rho: neighbor-cell walk (1 x b128 load per candidate) ----
        float S = 0.f;
        cell_walk(cix, ciy, ciz, ccnt, lane, [&](int j) {
            float4 P = ssp[j];
            float ddx = xi - P.x, ddy = yi - P.y, ddz = zi - P.z;
            float d2 = fmaf(ddx,ddx,EPS); d2 = fmaf(ddy,ddy,d2); d2 = fmaf(ddz,ddz,d2);
            float t  = fmaxf(RADIUS - __builtin_amdgcn_sqrtf(d2), 0.f);
            S = fmaf(t*t, t, S);
        });
        for (int off = 32; off > 0; off >>= 1) S += __shfl_down(S, off);
        if (lane == 0) {
            const float ts  = RADIUS - __builtin_amdgcn_sqrtf(EPS);  // exact self-term
            const float TS3 = ts*ts*ts;
            const float k3  = 3.f * SPIKY_C * STIFFNESS;             // L = -3C*lam
            store_dc(&lam[i], k3 * (SPIKY_C * (S - TS3) - DENSITY_REST));
        }
        grid_barrier(bar_ws, ++phase, ngroups);

        // ---- stage L into .w of sorted slots (coherent sc1 reads) ----
        {
            float4 l4 = load_dc4(((const float4*)lam) + tid);
            ssp[p.x].w = l4.x; ssp[p.y].w = l4.y; ssp[p.z].w = l4.z; ssp[p.w].w = l4.w;
        }
        float Li = load_dc(&lam[i]);
        __syncthreads();

        // ---- delta: neighbor-cell walk (x,y,z,L in one b128) ----
        float ax = 0.f, ay = 0.f, az = 0.f;
        cell_walk(cix, ciy, ciz, ccnt, lane, [&](int j) {
            float4 P = ssp[j];
            float ddx = xi - P.x, ddy = yi - P.y, ddz = zi - P.z;
            float d2 = fmaf(ddx,ddx,EPS); d2 = fmaf(ddy,ddy,d2); d2 = fmaf(ddz,ddz,d2);
            float rinv = __builtin_amdgcn_rsqf(d2);
            float t  = fmaxf(RADIUS - d2*rinv, 0.f);
            float cf = (Li + P.w) * (t*t) * rinv;
            ax = fmaf(cf, ddx, ax); ay = fmaf(cf, ddy, ay); az = fmaf(cf, ddz, az);
        });
        for (int off = 32; off > 0; off >>= 1) {
            ax += __shfl_down(ax, off); ay += __shfl_down(ay, off); az += __shfl_down(az, off);
        }
        if (lane == 0) {
            float nx = xi + ax, ny = yi + ay, nz = zi + az;
            store_dc(&px[i], nx); store_dc(&py[i], ny); store_dc(&pz[i], nz);
            if (last) {
                out[3*i+0] = nx; out[3*i+1] = ny; out[3*i+2] = nz;
                store_dc(&vnx[i], (nx - locs[3*i+0]) * (1.0f/DT));
                store_dc(&vny[i], (ny - locs[3*i+1]) * (1.0f/DT));
                store_dc(&vnz[i], (nz - locs[3*i+2]) * (1.0f/DT));
            }
        }
        grid_barrier(bar_ws, ++phase, ngroups);

        // ---- rebuild cell list from updated pred (coherent sc1 reads) ----
        BX = load_dc4(((const float4*)px) + tid);
        BY = load_dc4(((const float4*)py) + tid);
        BZ = load_dc4(((const float4*)pz) + tid);
        p  = build_cells(BX, BY, BZ, ssp, ccnt, wtot, tid);
        xi = load_dc(&px[i]); yi = load_dc(&py[i]); zi = load_dc(&pz[i]);
    }

    // ---- XSPH viscosity: stage new_vel sorted (AoS), then neighbor-cell walk ----
    {
        float4 a4 = load_dc4(((const float4*)vnx) + tid);
        float4 b4 = load_dc4(((const float4*)vny) + tid);
        float4 c4 = load_dc4(((const float4*)vnz) + tid);
        svp[p.x] = make_float4(a4.x, b4.x, c4.x, 0.f);
        svp[p.y] = make_float4(a4.y, b4.y, c4.y, 0.f);
        svp[p.z] = make_float4(a4.z, b4.z, c4.z, 0.f);
        svp[p.w] = make_float4(a4.w, b4.w, c4.w, 0.f);
    }
    const float vix = load_dc(&vnx[i]), viy = load_dc(&vny[i]), viz = load_dc(&vnz[i]);
    __syncthreads();

    const int cix = cell_coord(xi), ciy = cell_coord(yi), ciz = cell_coord(zi);
    float sw = 0.f, sax = 0.f, say = 0.f, saz = 0.f;
    cell_walk(cix, ciy, ciz, ccnt, lane, [&](int j) {
        float4 P = ssp[j];
        float4 V = svp[j];
        float ddx = xi - P.x, ddy = yi - P.y, ddz = zi - P.z;
        float d2 = fmaf(ddx,ddx,EPS); d2 = fmaf(ddy,ddy,d2); d2 = fmaf(ddz,ddz,d2);
        float t  = fmaxf(RADIUS - __builtin_amdgcn_sqrtf(d2), 0.f);
        float w  = t*t*t;
        sw += w;
        sax = fmaf(w, V.x, sax); say = fmaf(w, V.y, say); saz = fmaf(w, V.z, saz);
    });
    for (int off = 32; off > 0; off >>= 1) {
        sw  += __shfl_down(sw, off);  sax += __shfl_down(sax, off);
        say += __shfl_down(say, off); saz += __shfl_down(saz, off);
    }
    if (lane == 0) {
        constexpr float K = VISCOSITY * DT / DENSITY_REST;
        const float KC = K * SPIKY_C;   // C folded here; self-term cancels exactly
        float nvx = vix + KC * (sax - sw * vix);
        float nvy = viy + KC * (say - sw * viy);
        float nvz = viz + KC * (saz - sw * viz);
        float vv = sqrtf(nvx*nvx + nvy*nvy + nvz*nvz);
        float s  = fminf(MAX_VEL / (vv + 1e-4f), 1.0f);
        out[3*NMAX + 3*i + 0] = nvx * s;
        out[3*NMAX + 3*i + 1] = nvy * s;
        out[3*NMAX + 3*i + 2] = nvz * s;
    }
}

extern "C" void kernel_launch(void* const* d_in, const int* in_sizes, int n_in,
                              void* d_out, int out_size, void* d_ws, size_t ws_size,
                              hipStream_t stream) {
    const float* locs = (const float*)d_in[0];
    const float* vel  = (const float*)d_in[1];
    const float4* locs4 = (const float4*)locs;
    const float4* vel4  = (const float4*)vel;
    float* out = (float*)d_out;
    int n = in_sizes[0] / 3;   // 4096

    float* w = (float*)d_ws;
    float* px  = w;        float* py  = px + n;   float* pz  = py + n;
    float* lam = pz + n;
    float* vnx = lam + n;  float* vny = vnx + n;  float* vnz = vny + n;
    unsigned int* bar_ws = (unsigned int*)(w + 10 * n);

    int nb = n / 16;   // 16 waves/block, 1 particle/wave -> 256 blocks

    // zero barrier region: ngroups + root + release words, 64B-strided
    int ngroups = nb / 16;
    (void)hipMemsetAsync((void*)bar_ws, 0, (size_t)(ngroups + 2) * 64, stream);

    k_fused<<<dim3(nb), dim3(NT), 0, stream>>>(locs4, vel4, locs, vel,
                                               px, py, pz, lam,
                                               vnx, vny, vnz,
                                               out, bar_ws, n);
}

// Round 11
// 104.763 us; speedup vs baseline: 1.9024x; 1.0634x over previous
//
#include <hip/hip_runtime.h>
#include <math.h>

#define NMAX  4096
#define NT    1024      // 16 waves/block, 1 particle/wave
#define NC    10        // cells per dim, cell size = RADIUS
#define NCELL 1000

// n assumed == 4096 (reference problem size).

constexpr float RADIUS       = 0.1f;
constexpr float DT           = 1.0f / 60.0f;
constexpr float MAX_VEL      = 3.0f;               // 0.5*0.1/DT
constexpr float VISCOSITY    = 60.0f;
constexpr float DENSITY_REST = 17510.1f;
constexpr float STIFFNESS    = 2.99e-11f;
constexpr float EPS          = 1e-8f;
constexpr float SPIKY_C      = (float)(15.0 / (3.14159265358979323846 * 1e-6)); // 15/(pi*R^6)

#define BAR_STRIDE 16   // uints (64 B) between barrier words

// Device-coherent scalar store (sc1): write-through past the non-coherent
// local L2 so peer XCDs can see it after the barrier.
__device__ __forceinline__ void store_dc(float* p, float v) {
    __hip_atomic_store(p, v, __ATOMIC_RELAXED, __HIP_MEMORY_SCOPE_AGENT);
}

// Device-coherent loads: agent-scope relaxed atomics bypass stale L1/L2 and
// read the coherence point directly (replaces acquire-fence invalidation).
__device__ __forceinline__ float load_dc(const float* p) {
    return __hip_atomic_load(p, __ATOMIC_RELAXED, __HIP_MEMORY_SCOPE_AGENT);
}
__device__ __forceinline__ float4 load_dc4(const float4* p) {
    const unsigned long long* q = (const unsigned long long*)p;
    unsigned long long a = __hip_atomic_load(q,     __ATOMIC_RELAXED, __HIP_MEMORY_SCOPE_AGENT);
    unsigned long long b = __hip_atomic_load(q + 1, __ATOMIC_RELAXED, __HIP_MEMORY_SCOPE_AGENT);
    float4 r;
    ((unsigned long long*)&r)[0] = a;
    ((unsigned long long*)&r)[1] = b;
    return r;
}

// Two-level tree grid barrier, monotonic phases (proven R4-R9). No acquire
// fence: cross-block data is read via load_dc/load_dc4. __syncthreads before
// arrival drains vmcnt, so prior sc1 stores are at the coherence point before
// the flag RMW; flag observed => data visible to sc1 loads.
__device__ __forceinline__ void grid_barrier(unsigned int* ws, unsigned int phase,
                                             unsigned int ngroups) {
    __syncthreads();
    if (threadIdx.x == 0) {
        const unsigned g = (unsigned)blockIdx.x >> 4;   // 16 blocks per group
        unsigned a = __hip_atomic_fetch_add(&ws[g * BAR_STRIDE], 1u,
                                            __ATOMIC_RELAXED, __HIP_MEMORY_SCOPE_AGENT);
        if (a == phase * 16u - 1u) {
            unsigned r = __hip_atomic_fetch_add(&ws[ngroups * BAR_STRIDE], 1u,
                                                __ATOMIC_RELAXED, __HIP_MEMORY_SCOPE_AGENT);
            if (r == phase * ngroups - 1u)
                __hip_atomic_store(&ws[(ngroups + 1u) * BAR_STRIDE], phase,
                                   __ATOMIC_RELAXED, __HIP_MEMORY_SCOPE_AGENT);
        }
        while (__hip_atomic_load(&ws[(ngroups + 1u) * BAR_STRIDE], __ATOMIC_RELAXED,
                                 __HIP_MEMORY_SCOPE_AGENT) < phase) {
            __builtin_amdgcn_s_sleep(1);
        }
    }
    __syncthreads();
}

__device__ __forceinline__ int cell_coord(float v) {
    int c = (int)floorf(v * 10.f);
    return min(max(c, 0), NC - 1);
}
__device__ __forceinline__ int cell_id(float x, float y, float z) {
    return (cell_coord(x) * NC + cell_coord(y)) * NC + cell_coord(z);
}

// Per-block counting-sort cell list (AoS float4, parallel scan). Rebuilt every
// iteration (exact pair sets required — frozen-order approximation failed R10).
__device__ __forceinline__ int4 build_cells(float4 BX, float4 BY, float4 BZ,
                                            float4* ssp, unsigned* ccnt,
                                            unsigned* wtot, int tid) {
    ccnt[tid] = 0;
    __syncthreads();
    int c0 = cell_id(BX.x, BY.x, BZ.x);
    int c1 = cell_id(BX.y, BY.y, BZ.y);
    int c2 = cell_id(BX.z, BY.z, BZ.z);
    int c3 = cell_id(BX.w, BY.w, BZ.w);
    atomicAdd(&ccnt[c0], 1u); atomicAdd(&ccnt[c1], 1u);
    atomicAdd(&ccnt[c2], 1u); atomicAdd(&ccnt[c3], 1u);
    __syncthreads();
    // all-wave parallel exclusive scan over 1024 entries: thread t = entry t
    {
        const int l = tid & 63, w = tid >> 6;
        unsigned v = ccnt[tid];
        unsigned incl = v;
        for (int off = 1; off < 64; off <<= 1) {
            unsigned u = __shfl_up(incl, off);
            if (l >= off) incl += u;
        }
        if (l == 63) wtot[w] = incl;        // per-wave total
        unsigned excl = incl - v;
        __syncthreads();
        if (tid < 16) {                     // exclusive scan of 16 wave totals
            unsigned tv = wtot[tid];
            unsigned ti = tv;
            for (int off = 1; off < 16; off <<= 1) {
                unsigned u = __shfl_up(ti, off);
                if (tid >= off) ti += u;
            }
            wtot[tid] = ti - tv;
        }
        __syncthreads();
        ccnt[tid] = excl + wtot[w];         // global exclusive start
    }
    __syncthreads();
    int4 p;
    p.x = (int)atomicAdd(&ccnt[c0], 1u); ssp[p.x] = make_float4(BX.x, BY.x, BZ.x, 0.f);
    p.y = (int)atomicAdd(&ccnt[c1], 1u); ssp[p.y] = make_float4(BX.y, BY.y, BZ.y, 0.f);
    p.z = (int)atomicAdd(&ccnt[c2], 1u); ssp[p.z] = make_float4(BX.z, BY.z, BZ.z, 0.f);
    p.w = (int)atomicAdd(&ccnt[c3], 1u); ssp[p.w] = make_float4(BX.w, BY.w, BZ.w, 0.f);
    __syncthreads();          // ccnt now holds cell END offsets; sorted array ready
    return p;
}

// FLATTENED neighborhood walk: lanes are partitioned across the 9 (dx,dy)
// z-column runs (7 lanes per run; lane 63 idle). Each lane reads its own run's
// [beg,end) from ccnt (no register arrays -> no scratch) and strides by 7.
// All 9 runs proceed concurrently: trip count = ceil(maxrun/7) ~ 2-3 instead
// of 9 serialized one-iteration runs at ~12/64 lane utilization.
template <typename F>
__device__ __forceinline__ void cell_walk(int cix, int ciy, int ciz,
                                          const unsigned* ccnt, int lane, F&& body) {
    const int r = lane / 7;              // run 0..8 (lane 63 -> 9: idle)
    const int o = lane - r * 7;          // offset within run
    if (r < 9) {
        const int nx = cix + (r / 3) - 1;
        const int ny = ciy + (r % 3) - 1;
        if ((unsigned)nx < (unsigned)NC && (unsigned)ny < (unsigned)NC) {
            const int zlo = max(ciz - 1, 0), zhi = min(ciz + 1, NC - 1);
            const int cb  = (nx * NC + ny) * NC;
            const int cA  = cb + zlo, cB = cb + zhi;
            const int beg = (cA > 0) ? (int)ccnt[cA - 1] : 0;
            const int end = (int)ccnt[cB];
            for (int j = beg + o; j < end; j += 7) body(j);
        }
    }
}

// ---------------- single fused kernel ----------------
// 256 blocks x 1024 threads (16 waves), 1 particle/wave, ~132 KB static LDS
// -> 1 block/CU, grid 256 = CU count, co-resident (plain launch).

__global__ __launch_bounds__(NT) void k_fused(const float4* __restrict__ locs4,
                                              const float4* __restrict__ vel4,
                                              const float* __restrict__ locs,
                                              const float* __restrict__ vel,
                                              float* __restrict__ px, float* __restrict__ py,
                                              float* __restrict__ pz,
                                              float* __restrict__ lam,
                                              float* __restrict__ vnx, float* __restrict__ vny,
                                              float* __restrict__ vnz,
                                              float* __restrict__ out,
                                              unsigned int* __restrict__ bar_ws, int n) {
    __shared__ float4 ssp[NMAX];        // 64 KB sorted (x,y,z,lam)
    __shared__ float4 svp[NMAX];        // 64 KB sorted (vx,vy,vz,0) for visc
    __shared__ unsigned ccnt[NT];       // 4 KB cell table (+pad)
    __shared__ unsigned wtot[16];       // wave totals for scan

    const int tid  = threadIdx.x;
    const int lane = tid & 63;
    const int wave = tid >> 6;
    const int i    = blockIdx.x * 16 + wave;            // owned particle (original idx)
    const unsigned ngroups = (unsigned)gridDim.x >> 4;
    unsigned phase = 0;
    (void)n;

    // ---- predict (registers) for this thread's 4 particles; build cell list 1 ----
    float4 BX, BY, BZ;
    {
        float lo[12], ve[12];
        *(float4*)&lo[0] = locs4[3*tid];   *(float4*)&lo[4] = locs4[3*tid+1]; *(float4*)&lo[8] = locs4[3*tid+2];
        *(float4*)&ve[0] = vel4[3*tid];    *(float4*)&ve[4] = vel4[3*tid+1];  *(float4*)&ve[8] = vel4[3*tid+2];
        float P[12];
#pragma unroll
        for (int q = 0; q < 4; ++q) {
            float vx = ve[3*q], vy = ve[3*q+1] - 9.8f * DT, vz = ve[3*q+2];
            float vv = sqrtf(vx*vx + vy*vy + vz*vz);
            float s  = fminf(MAX_VEL / (vv + 1e-4f), 1.0f);
            P[3*q]   = lo[3*q]   + DT * vx * s;
            P[3*q+1] = lo[3*q+1] + DT * vy * s;
            P[3*q+2] = lo[3*q+2] + DT * vz * s;
        }
        BX = make_float4(P[0], P[3], P[6], P[9]);
        BY = make_float4(P[1], P[4], P[7], P[10]);
        BZ = make_float4(P[2], P[5], P[8], P[11]);
    }
    int4 p = build_cells(BX, BY, BZ, ssp, ccnt, wtot, tid);

    // own predicted position (identical expression tree -> identical rounding)
    float xi, yi, zi;
    {
        float vx = vel[3*i], vy = vel[3*i+1] - 9.8f * DT, vz = vel[3*i+2];
        float vv = sqrtf(vx*vx + vy*vy + vz*vz);
        float s  = fminf(MAX_VEL / (vv + 1e-4f), 1.0f);
        xi = locs[3*i]   + DT * vx * s;
        yi = locs[3*i+1] + DT * vy * s;
        zi = locs[3*i+2] + DT * vz * s;
    }

    for (int it = 0; it < 3; ++it) {
        const bool last = (it == 2);
        const int cix = cell_coord(xi), ciy = cell_coord(yi), ciz = cell_coord(zi);

        // ---- rho: flattened neighbor-cell walk ----
        float S = 0.f;
        cell_walk(cix, ciy, ciz, ccnt, lane, [&](int j) {
            float4 P = ssp[j];
            float ddx = xi - P.x, ddy = yi - P.y, ddz = zi - P.z;
            float d2 = fmaf(ddx,ddx,EPS); d2 = fmaf(ddy,ddy,d2); d2 = fmaf(ddz,ddz,d2);
            float t  = fmaxf(RADIUS - __builtin_amdgcn_sqrtf(d2), 0.f);
            S = fmaf(t*t, t, S);
        });
        for (int off = 32; off > 0; off >>= 1) S += __shfl_down(S, off);
        if (lane == 0) {
            const float ts  = RADIUS - __builtin_amdgcn_sqrtf(EPS);  // exact self-term
            const float TS3 = ts*ts*ts;
            const float k3  = 3.f * SPIKY_C * STIFFNESS;             // L = -3C*lam
            store_dc(&lam[i], k3 * (SPIKY_C * (S - TS3) - DENSITY_REST));
        }
        grid_barrier(bar_ws, ++phase, ngroups);

        // ---- stage L into .w of sorted slots (coherent sc1 reads) ----
        {
            float4 l4 = load_dc4(((const float4*)lam) + tid);
            ssp[p.x].w = l4.x; ssp[p.y].w = l4.y; ssp[p.z].w = l4.z; ssp[p.w].w = l4.w;
        }
        float Li = load_dc(&lam[i]);
        __syncthreads();

        // ---- delta: flattened neighbor-cell walk (x,y,z,L in one b128) ----
        float ax = 0.f, ay = 0.f, az = 0.f;
        cell_walk(cix, ciy, ciz, ccnt, lane, [&](int j) {
            float4 P = ssp[j];
            float ddx = xi - P.x, ddy = yi - P.y, ddz = zi - P.z;
            float d2 = fmaf(ddx,ddx,EPS); d2 = fmaf(ddy,ddy,d2); d2 = fmaf(ddz,ddz,d2);
            float rinv = __builtin_amdgcn_rsqf(d2);
            float t  = fmaxf(RADIUS - d2*rinv, 0.f);
            float cf = (Li + P.w) * (t*t) * rinv;
            ax = fmaf(cf, ddx, ax); ay = fmaf(cf, ddy, ay); az = fmaf(cf, ddz, az);
        });
        for (int off = 32; off > 0; off >>= 1) {
            ax += __shfl_down(ax, off); ay += __shfl_down(ay, off); az += __shfl_down(az, off);
        }
        if (lane == 0) {
            float nx = xi + ax, ny = yi + ay, nz = zi + az;
            store_dc(&px[i], nx); store_dc(&py[i], ny); store_dc(&pz[i], nz);
            if (last) {
                out[3*i+0] = nx; out[3*i+1] = ny; out[3*i+2] = nz;
                store_dc(&vnx[i], (nx - locs[3*i+0]) * (1.0f/DT));
                store_dc(&vny[i], (ny - locs[3*i+1]) * (1.0f/DT));
                store_dc(&vnz[i], (nz - locs[3*i+2]) * (1.0f/DT));
            }
        }
        grid_barrier(bar_ws, ++phase, ngroups);

        // ---- rebuild cell list from updated pred (coherent sc1 reads) ----
        BX = load_dc4(((const float4*)px) + tid);
        BY = load_dc4(((const float4*)py) + tid);
        BZ = load_dc4(((const float4*)pz) + tid);
        p  = build_cells(BX, BY, BZ, ssp, ccnt, wtot, tid);
        xi = load_dc(&px[i]); yi = load_dc(&py[i]); zi = load_dc(&pz[i]);
    }

    // ---- XSPH viscosity: stage new_vel sorted (AoS), then flattened walk ----
    {
        float4 a4 = load_dc4(((const float4*)vnx) + tid);
        float4 b4 = load_dc4(((const float4*)vny) + tid);
        float4 c4 = load_dc4(((const float4*)vnz) + tid);
        svp[p.x] = make_float4(a4.x, b4.x, c4.x, 0.f);
        svp[p.y] = make_float4(a4.y, b4.y, c4.y, 0.f);
        svp[p.z] = make_float4(a4.z, b4.z, c4.z, 0.f);
        svp[p.w] = make_float4(a4.w, b4.w, c4.w, 0.f);
    }
    const float vix = load_dc(&vnx[i]), viy = load_dc(&vny[i]), viz = load_dc(&vnz[i]);
    __syncthreads();

    const int cix = cell_coord(xi), ciy = cell_coord(yi), ciz = cell_coord(zi);
    float sw = 0.f, sax = 0.f, say = 0.f, saz = 0.f;
    cell_walk(cix, ciy, ciz, ccnt, lane, [&](int j) {
        float4 P = ssp[j];
        float4 V = svp[j];
        float ddx = xi - P.x, ddy = yi - P.y, ddz = zi - P.z;
        float d2 = fmaf(ddx,ddx,EPS); d2 = fmaf(ddy,ddy,d2); d2 = fmaf(ddz,ddz,d2);
        float t  = fmaxf(RADIUS - __builtin_amdgcn_sqrtf(d2), 0.f);
        float w  = t*t*t;
        sw += w;
        sax = fmaf(w, V.x, sax); say = fmaf(w, V.y, say); saz = fmaf(w, V.z, saz);
    });
    for (int off = 32; off > 0; off >>= 1) {
        sw  += __shfl_down(sw, off);  sax += __shfl_down(sax, off);
        say += __shfl_down(say, off); saz += __shfl_down(saz, off);
    }
    if (lane == 0) {
        constexpr float K = VISCOSITY * DT / DENSITY_REST;
        const float KC = K * SPIKY_C;   // C folded here; self-term cancels exactly
        float nvx = vix + KC * (sax - sw * vix);
        float nvy = viy + KC * (say - sw * viy);
        float nvz = viz + KC * (saz - sw * viz);
        float vv = sqrtf(nvx*nvx + nvy*nvy + nvz*nvz);
        float s  = fminf(MAX_VEL / (vv + 1e-4f), 1.0f);
        out[3*NMAX + 3*i + 0] = nvx * s;
        out[3*NMAX + 3*i + 1] = nvy * s;
        out[3*NMAX + 3*i + 2] = nvz * s;
    }
}

extern "C" void kernel_launch(void* const* d_in, const int* in_sizes, int n_in,
                              void* d_out, int out_size, void* d_ws, size_t ws_size,
                              hipStream_t stream) {
    const float* locs = (const float*)d_in[0];
    const float* vel  = (const float*)d_in[1];
    const float4* locs4 = (const float4*)locs;
    const float4* vel4  = (const float4*)vel;
    float* out = (float*)d_out;
    int n = in_sizes[0] / 3;   // 4096

    float* w = (float*)d_ws;
    float* px  = w;        float* py  = px + n;   float* pz  = py + n;
    float* lam = pz + n;
    float* vnx = lam + n;  float* vny = vnx + n;  float* vnz = vny + n;
    unsigned int* bar_ws = (unsigned int*)(w + 10 * n);

    int nb = n / 16;   // 16 waves/block, 1 particle/wave -> 256 blocks
    int ngroups = nb / 16;
    (void)hipMemsetAsync((void*)bar_ws, 0, (size_t)(ngroups + 2) * 64, stream);

    k_fused<<<dim3(nb), dim3(NT), 0, stream>>>(locs4, vel4, locs, vel,
                                               px, py, pz, lam,
                                               vnx, vny, vnz,
                                               out, bar_ws, n);
}

// Round 13
// 102.012 us; speedup vs baseline: 1.9537x; 1.0270x over previous
//
#include <hip/hip_runtime.h>
#include <math.h>

#define NMAX  4096
#define NT    1024      // 16 waves/block, 1 particle/wave
#define NC    10        // cells per dim, cell size = RADIUS
#define NCELL 1000

// n assumed == 4096 (reference problem size).

constexpr float RADIUS       = 0.1f;
constexpr float DT           = 1.0f / 60.0f;
constexpr float MAX_VEL      = 3.0f;               // 0.5*0.1/DT
constexpr float VISCOSITY    = 60.0f;
constexpr float DENSITY_REST = 17510.1f;
constexpr float STIFFNESS    = 2.99e-11f;
constexpr float EPS          = 1e-8f;
constexpr float SPIKY_C      = (float)(15.0 / (3.14159265358979323846 * 1e-6)); // 15/(pi*R^6)

#define BAR_STRIDE 16   // uints (64 B) between barrier words
#define NGROUPS    16   // 256 blocks / 16 per group

// Persistent barrier words in device BSS: zeroed at module load, never touched
// by the harness (it only poisons d_ws). Counters are MONOTONIC across all
// launches/replays; all barrier logic is RELATIVE to the release value read at
// kernel entry, so no host-side init (no memset dispatch) is needed.
__device__ unsigned bar_dev[(NGROUPS + 2) * BAR_STRIDE];

// Device-coherent scalar store (sc1): write-through past the non-coherent
// local L2 so peer XCDs can see it after the barrier.
__device__ __forceinline__ void store_dc(float* p, float v) {
    __hip_atomic_store(p, v, __ATOMIC_RELAXED, __HIP_MEMORY_SCOPE_AGENT);
}

// Device-coherent loads: agent-scope relaxed atomics bypass stale L1/L2 and
// read the coherence point directly (replaces acquire-fence invalidation).
__device__ __forceinline__ float load_dc(const float* p) {
    return __hip_atomic_load(p, __ATOMIC_RELAXED, __HIP_MEMORY_SCOPE_AGENT);
}
__device__ __forceinline__ float4 load_dc4(const float4* p) {
    const unsigned long long* q = (const unsigned long long*)p;
    unsigned long long a = __hip_atomic_load(q,     __ATOMIC_RELAXED, __HIP_MEMORY_SCOPE_AGENT);
    unsigned long long b = __hip_atomic_load(q + 1, __ATOMIC_RELAXED, __HIP_MEMORY_SCOPE_AGENT);
    float4 r;
    ((unsigned long long*)&r)[0] = a;
    ((unsigned long long*)&r)[1] = b;
    return r;
}

// Two-level tree grid barrier, monotonic & relative (no reset, no memset).
// Group counters advance by exactly 16 per phase and root by NGROUPS per
// phase, and every launch completes all its phases -> at launch entry all
// counters sit at multiples of 16, so "last arriver" tests are (x & 15)==15.
// Release is a counter incremented once per completed phase; blocks wait for
// release >= R0 + phase (wrap-safe compare). R0 is read by thread 0 at kernel
// entry: release for this launch's phase 1 cannot advance until this block
// itself arrives, which is after the read (and the read is drained by the
// first __syncthreads inside build_cells before any arrival).
__device__ __forceinline__ void grid_barrier(unsigned R0, unsigned phase) {
    __syncthreads();
    if (threadIdx.x == 0) {
        const unsigned g = (unsigned)blockIdx.x >> 4;   // 16 blocks per group
        unsigned a = __hip_atomic_fetch_add(&bar_dev[g * BAR_STRIDE], 1u,
                                            __ATOMIC_RELAXED, __HIP_MEMORY_SCOPE_AGENT);
        if ((a & 15u) == 15u) {                         // last arriver of this group
            unsigned r = __hip_atomic_fetch_add(&bar_dev[NGROUPS * BAR_STRIDE], 1u,
                                                __ATOMIC_RELAXED, __HIP_MEMORY_SCOPE_AGENT);
            if ((r & (NGROUPS - 1u)) == NGROUPS - 1u)   // last group overall
                __hip_atomic_fetch_add(&bar_dev[(NGROUPS + 1u) * BAR_STRIDE], 1u,
                                       __ATOMIC_RELAXED, __HIP_MEMORY_SCOPE_AGENT);
        }
        while ((int)(__hip_atomic_load(&bar_dev[(NGROUPS + 1u) * BAR_STRIDE],
                                       __ATOMIC_RELAXED, __HIP_MEMORY_SCOPE_AGENT)
                     - (R0 + phase)) < 0) {
            __builtin_amdgcn_s_sleep(1);
        }
    }
    __syncthreads();
}

__device__ __forceinline__ int cell_coord(float v) {
    int c = (int)floorf(v * 10.f);
    return min(max(c, 0), NC - 1);
}
__device__ __forceinline__ int cell_id(float x, float y, float z) {
    return (cell_coord(x) * NC + cell_coord(y)) * NC + cell_coord(z);
}

// Per-block counting-sort cell list (AoS float4, parallel scan). Rebuilt every
// iteration (exact pair sets required — frozen-order approximation failed R10).
__device__ __forceinline__ int4 build_cells(float4 BX, float4 BY, float4 BZ,
                                            float4* ssp, unsigned* ccnt,
                                            unsigned* wtot, int tid) {
    ccnt[tid] = 0;
    __syncthreads();
    int c0 = cell_id(BX.x, BY.x, BZ.x);
    int c1 = cell_id(BX.y, BY.y, BZ.y);
    int c2 = cell_id(BX.z, BY.z, BZ.z);
    int c3 = cell_id(BX.w, BY.w, BZ.w);
    atomicAdd(&ccnt[c0], 1u); atomicAdd(&ccnt[c1], 1u);
    atomicAdd(&ccnt[c2], 1u); atomicAdd(&ccnt[c3], 1u);
    __syncthreads();
    // all-wave parallel exclusive scan over 1024 entries: thread t = entry t
    {
        const int l = tid & 63, w = tid >> 6;
        unsigned v = ccnt[tid];
        unsigned incl = v;
        for (int off = 1; off < 64; off <<= 1) {
            unsigned u = __shfl_up(incl, off);
            if (l >= off) incl += u;
        }
        if (l == 63) wtot[w] = incl;        // per-wave total
        unsigned excl = incl - v;
        __syncthreads();
        if (tid < 16) {                     // exclusive scan of 16 wave totals
            unsigned tv = wtot[tid];
            unsigned ti = tv;
            for (int off = 1; off < 16; off <<= 1) {
                unsigned u = __shfl_up(ti, off);
                if (tid >= off) ti += u;
            }
            wtot[tid] = ti - tv;
        }
        __syncthreads();
        ccnt[tid] = excl + wtot[w];         // global exclusive start
    }
    __syncthreads();
    int4 p;
    p.x = (int)atomicAdd(&ccnt[c0], 1u); ssp[p.x] = make_float4(BX.x, BY.x, BZ.x, 0.f);
    p.y = (int)atomicAdd(&ccnt[c1], 1u); ssp[p.y] = make_float4(BX.y, BY.y, BZ.y, 0.f);
    p.z = (int)atomicAdd(&ccnt[c2], 1u); ssp[p.z] = make_float4(BX.z, BY.z, BZ.z, 0.f);
    p.w = (int)atomicAdd(&ccnt[c3], 1u); ssp[p.w] = make_float4(BX.w, BY.w, BZ.w, 0.f);
    __syncthreads();          // ccnt now holds cell END offsets; sorted array ready
    return p;
}

// Per-lane run boundaries for the FLATTENED neighborhood walk: lanes are
// partitioned across the 9 (dx,dy) z-column runs (7 lanes per run; lane 63
// idle). Computed ONCE per iteration (ccnt is stable between builds) and
// reused for both the rho and delta walks.
__device__ __forceinline__ void walk_bounds(int cix, int ciy, int ciz,
                                            const unsigned* ccnt, int lane,
                                            int& wbeg, int& wend) {
    const int r = lane / 7;              // run 0..8 (lane 63 -> 9: idle)
    wbeg = 0; wend = 0;
    if (r < 9) {
        const int nx = cix + (r / 3) - 1;
        const int ny = ciy + (r % 3) - 1;
        if ((unsigned)nx < (unsigned)NC && (unsigned)ny < (unsigned)NC) {
            const int zlo = max(ciz - 1, 0), zhi = min(ciz + 1, NC - 1);
            const int cb  = (nx * NC + ny) * NC;
            const int cA  = cb + zlo, cB = cb + zhi;
            wbeg = (cA > 0) ? (int)ccnt[cA - 1] : 0;
            wend = (int)ccnt[cB];
        }
    }
}

// ---------------- single fused kernel ----------------
// 256 blocks x 1024 threads (16 waves), 1 particle/wave, ~132 KB static LDS
// -> 1 block/CU, grid 256 = CU count, co-resident (plain launch).

__global__ __launch_bounds__(NT) void k_fused(const float4* __restrict__ locs4,
                                              const float4* __restrict__ vel4,
                                              const float* __restrict__ locs,
                                              const float* __restrict__ vel,
                                              float* __restrict__ px, float* __restrict__ py,
                                              float* __restrict__ pz,
                                              float* __restrict__ lam,
                                              float* __restrict__ vnx, float* __restrict__ vny,
                                              float* __restrict__ vnz,
                                              float* __restrict__ out, int n) {
    __shared__ float4 ssp[NMAX];        // 64 KB sorted (x,y,z,lam)
    __shared__ float4 svp[NMAX];        // 64 KB sorted (vx,vy,vz,0) for visc
    __shared__ unsigned ccnt[NT];       // 4 KB cell table (+pad)
    __shared__ unsigned wtot[16];       // wave totals for scan

    const int tid  = threadIdx.x;
    const int lane = tid & 63;
    const int wave = tid >> 6;
    const int i    = blockIdx.x * 16 + wave;            // owned particle (original idx)
    const int wo   = lane - (lane / 7) * 7;             // offset within walk run
    unsigned phase = 0;
    (void)n;

    // Read release base BEFORE any arrival (drained by first __syncthreads).
    unsigned R0 = 0;
    if (tid == 0)
        R0 = __hip_atomic_load(&bar_dev[(NGROUPS + 1u) * BAR_STRIDE],
                               __ATOMIC_RELAXED, __HIP_MEMORY_SCOPE_AGENT);

    // ---- predict (registers) for this thread's 4 particles; build cell list 1 ----
    float4 BX, BY, BZ;
    {
        float lo[12], ve[12];
        *(float4*)&lo[0] = locs4[3*tid];   *(float4*)&lo[4] = locs4[3*tid+1]; *(float4*)&lo[8] = locs4[3*tid+2];
        *(float4*)&ve[0] = vel4[3*tid];    *(float4*)&ve[4] = vel4[3*tid+1];  *(float4*)&ve[8] = vel4[3*tid+2];
        float P[12];
#pragma unroll
        for (int q = 0; q < 4; ++q) {
            float vx = ve[3*q], vy = ve[3*q+1] - 9.8f * DT, vz = ve[3*q+2];
            float vv = sqrtf(vx*vx + vy*vy + vz*vz);
            float s  = fminf(MAX_VEL / (vv + 1e-4f), 1.0f);
            P[3*q]   = lo[3*q]   + DT * vx * s;
            P[3*q+1] = lo[3*q+1] + DT * vy * s;
            P[3*q+2] = lo[3*q+2] + DT * vz * s;
        }
        BX = make_float4(P[0], P[3], P[6], P[9]);
        BY = make_float4(P[1], P[4], P[7], P[10]);
        BZ = make_float4(P[2], P[5], P[8], P[11]);
    }
    int4 p = build_cells(BX, BY, BZ, ssp, ccnt, wtot, tid);

    // own predicted position (identical expression tree -> identical rounding)
    float xi, yi, zi;
    {
        float vx = vel[3*i], vy = vel[3*i+1] - 9.8f * DT, vz = vel[3*i+2];
        float vv = sqrtf(vx*vx + vy*vy + vz*vz);
        float s  = fminf(MAX_VEL / (vv + 1e-4f), 1.0f);
        xi = locs[3*i]   + DT * vx * s;
        yi = locs[3*i+1] + DT * vy * s;
        zi = locs[3*i+2] + DT * vz * s;
    }

    for (int it = 0; it < 3; ++it) {
        const bool last = (it == 2);

        // per-iteration walk boundaries (reused by rho AND delta)
        int wbeg, wend;
        walk_bounds(cell_coord(xi), cell_coord(yi), cell_coord(zi), ccnt, lane, wbeg, wend);

        // ---- rho: flattened neighbor-cell walk ----
        float S = 0.f;
        for (int j = wbeg + wo; j < wend; j += 7) {
            float4 P = ssp[j];
            float ddx = xi - P.x, ddy = yi - P.y, ddz = zi - P.z;
            float d2 = fmaf(ddx,ddx,EPS); d2 = fmaf(ddy,ddy,d2); d2 = fmaf(ddz,ddz,d2);
            float t  = fmaxf(RADIUS - __builtin_amdgcn_sqrtf(d2), 0.f);
            S = fmaf(t*t, t, S);
        }
        for (int off = 32; off > 0; off >>= 1) S += __shfl_down(S, off);
        if (lane == 0) {
            const float ts  = RADIUS - __builtin_amdgcn_sqrtf(EPS);  // exact self-term
            const float TS3 = ts*ts*ts;
            const float k3  = 3.f * SPIKY_C * STIFFNESS;             // L = -3C*lam
            store_dc(&lam[i], k3 * (SPIKY_C * (S - TS3) - DENSITY_REST));
        }
        grid_barrier(R0, ++phase);

        // ---- stage L into .w of sorted slots (coherent sc1 reads) ----
        {
            float4 l4 = load_dc4(((const float4*)lam) + tid);
            ssp[p.x].w = l4.x; ssp[p.y].w = l4.y; ssp[p.z].w = l4.z; ssp[p.w].w = l4.w;
        }
        float Li = load_dc(&lam[i]);
        __syncthreads();

        // ---- delta: same boundaries, (x,y,z,L) in one b128 ----
        float ax = 0.f, ay = 0.f, az = 0.f;
        for (int j = wbeg + wo; j < wend; j += 7) {
            float4 P = ssp[j];
            float ddx = xi - P.x, ddy = yi - P.y, ddz = zi - P.z;
            float d2 = fmaf(ddx,ddx,EPS); d2 = fmaf(ddy,ddy,d2); d2 = fmaf(ddz,ddz,d2);
            float rinv = __builtin_amdgcn_rsqf(d2);
            float t  = fmaxf(RADIUS - d2*rinv, 0.f);
            float cf = (Li + P.w) * (t*t) * rinv;
            ax = fmaf(cf, ddx, ax); ay = fmaf(cf, ddy, ay); az = fmaf(cf, ddz, az);
        }
        for (int off = 32; off > 0; off >>= 1) {
            ax += __shfl_down(ax, off); ay += __shfl_down(ay, off); az += __shfl_down(az, off);
        }
        if (lane == 0) {
            float nx = xi + ax, ny = yi + ay, nz = zi + az;
            store_dc(&px[i], nx); store_dc(&py[i], ny); store_dc(&pz[i], nz);
            if (last) {
                out[3*i+0] = nx; out[3*i+1] = ny; out[3*i+2] = nz;
                store_dc(&vnx[i], (nx - locs[3*i+0]) * (1.0f/DT));
                store_dc(&vny[i], (ny - locs[3*i+1]) * (1.0f/DT));
                store_dc(&vnz[i], (nz - locs[3*i+2]) * (1.0f/DT));
            }
        }
        grid_barrier(R0, ++phase);

        // ---- rebuild cell list from updated pred (coherent sc1 reads) ----
        BX = load_dc4(((const float4*)px) + tid);
        BY = load_dc4(((const float4*)py) + tid);
        BZ = load_dc4(((const float4*)pz) + tid);
        p  = build_cells(BX, BY, BZ, ssp, ccnt, wtot, tid);
        xi = load_dc(&px[i]); yi = load_dc(&py[i]); zi = load_dc(&pz[i]);
    }

    // ---- XSPH viscosity: stage new_vel sorted (AoS), then flattened walk ----
    {
        float4 a4 = load_dc4(((const float4*)vnx) + tid);
        float4 b4 = load_dc4(((const float4*)vny) + tid);
        float4 c4 = load_dc4(((const float4*)vnz) + tid);
        svp[p.x] = make_float4(a4.x, b4.x, c4.x, 0.f);
        svp[p.y] = make_float4(a4.y, b4.y, c4.y, 0.f);
        svp[p.z] = make_float4(a4.z, b4.z, c4.z, 0.f);
        svp[p.w] = make_float4(a4.w, b4.w, c4.w, 0.f);
    }
    const float vix = load_dc(&vnx[i]), viy = load_dc(&vny[i]), viz = load_dc(&vnz[i]);
    __syncthreads();

    int wbeg, wend;
    walk_bounds(cell_coord(xi), cell_coord(yi), cell_coord(zi), ccnt, lane, wbeg, wend);
    float sw = 0.f, sax = 0.f, say = 0.f, saz = 0.f;
    for (int j = wbeg + wo; j < wend; j += 7) {
        float4 P = ssp[j];
        float4 V = svp[j];
        float ddx = xi - P.x, ddy = yi - P.y, ddz = zi - P.z;
        float d2 = fmaf(ddx,ddx,EPS); d2 = fmaf(ddy,ddy,d2); d2 = fmaf(ddz,ddz,d2);
        float t  = fmaxf(RADIUS - __builtin_amdgcn_sqrtf(d2), 0.f);
        float w  = t*t*t;
        sw += w;
        sax = fmaf(w, V.x, sax); say = fmaf(w, V.y, say); saz = fmaf(w, V.z, saz);
    }
    for (int off = 32; off > 0; off >>= 1) {
        sw  += __shfl_down(sw, off);  sax += __shfl_down(sax, off);
        say += __shfl_down(say, off); saz += __shfl_down(saz, off);
    }
    if (lane == 0) {
        constexpr float K = VISCOSITY * DT / DENSITY_REST;
        const float KC = K * SPIKY_C;   // C folded here; self-term cancels exactly
        float nvx = vix + KC * (sax - sw * vix);
        float nvy = viy + KC * (say - sw * viy);
        float nvz = viz + KC * (saz - sw * viz);
        float vv = sqrtf(nvx*nvx + nvy*nvy + nvz*nvz);
        float s  = fminf(MAX_VEL / (vv + 1e-4f), 1.0f);
        out[3*NMAX + 3*i + 0] = nvx * s;
        out[3*NMAX + 3*i + 1] = nvy * s;
        out[3*NMAX + 3*i + 2] = nvz * s;
    }
}

extern "C" void kernel_launch(void* const* d_in, const int* in_sizes, int n_in,
                              void* d_out, int out_size, void* d_ws, size_t ws_size,
                              hipStream_t stream) {
    const float* locs = (const float*)d_in[0];
    const float* vel  = (const float*)d_in[1];
    const float4* locs4 = (const float4*)locs;
    const float4* vel4  = (const float4*)vel;
    float* out = (float*)d_out;
    int n = in_sizes[0] / 3;   // 4096

    float* w = (float*)d_ws;
    float* px  = w;        float* py  = px + n;   float* pz  = py + n;
    float* lam = pz + n;
    float* vnx = lam + n;  float* vny = vnx + n;  float* vnz = vny + n;

    int nb = n / 16;   // 16 waves/block, 1 particle/wave -> 256 blocks

    k_fused<<<dim3(nb), dim3(NT), 0, stream>>>(locs4, vel4, locs, vel,
                                               px, py, pz, lam,
                                               vnx, vny, vnz,
                                               out, n);
}